// Round 13
// baseline (852.733 us; speedup 1.0000x reference)
//
#include <hip/hip_runtime.h>
#include <math.h>

// Shapes (fixed by setup_inputs)
#define BATCH 8
#define TSEQ 2048
#define CIN 3
#define WIN 5
#define LSEQ 2044          // T - WIN + 1
#define LH 2045            // LSEQ + 1 (cls token appended)
#define LHP 2048           // padded token rows for bf16 h buffers
#define DIM 128
#define DEPTH 4
#define DIN 256            // d_inner
#define NH 4               // heads
#define PDIM 64            // headdim
#define NSTATE 64          // d_state
#define CONVD 384          // d_inner + 2*d_state
#define DPROJ 644          // 2*d_inner + 2*d_state + nheads
#define DPROJP 656         // padded j rows for bf16 weight (41*16)
#define QC 64              // chunk length
#define NCH 32             // number of chunks
#define LDP 68             // padded LDS row stride
#define FTR 32             // tokens per k_front block

typedef __attribute__((ext_vector_type(8))) short bf16x8;
typedef __attribute__((ext_vector_type(4))) float f32x4;

__device__ __forceinline__ float sigmoidf_(float x){ return 1.f/(1.f+__expf(-x)); }
__device__ __forceinline__ float siluf_(float x){ return x*sigmoidf_(x); }
__device__ __forceinline__ unsigned short f2bf(float f){   // RNE fp32->bf16
  unsigned int u = __float_as_uint(f);
  return (unsigned short)((u + 0x7FFFu + ((u >> 16) & 1u)) >> 16);
}
__device__ __forceinline__ float bf2f(unsigned short u){
  return __uint_as_float(((unsigned int)u) << 16);
}

// ---------------------------------------------------------------- weight transpose (ow only)
__global__ void __launch_bounds__(256) k_transpose(
    const float* __restrict__ src, float* __restrict__ dst, int R, int C) {
  __shared__ float tile[64][65];
  const float* s = src + (size_t)blockIdx.z*R*C;
  float* d = dst + (size_t)blockIdx.z*R*C;
  int r0 = blockIdx.y*64, c0 = blockIdx.x*64;
  int tx = threadIdx.x & 63, ty = threadIdx.x >> 6;
  for (int rr = ty; rr < 64; rr += 4) {
    int r = r0 + rr, c = c0 + tx;
    if (r < R && c < C) tile[rr][tx] = s[(size_t)r*C + c];
  }
  __syncthreads();
  for (int cc = ty; cc < 64; cc += 4) {
    int c = c0 + cc, r = r0 + tx;
    if (c < C && r < R) d[(size_t)c*R + r] = tile[tx][cc];
  }
}

// inw: [4][644][128] fp32 -> hi/lo [4][656][128] bf16 (pad rows zero)
__global__ void __launch_bounds__(256) k_cast_w(
    const float* __restrict__ w, unsigned short* __restrict__ wH,
    unsigned short* __restrict__ wL) {
  size_t gid = (size_t)blockIdx.x*256 + threadIdx.x;
  size_t e = gid*4;
  if (e >= (size_t)DEPTH*DPROJP*DIM) return;
  int ly = (int)(e / (DPROJP*DIM));
  int rem = (int)(e - (size_t)ly*DPROJP*DIM);
  int row = rem >> 7, col = rem & 127;
  float4 v = make_float4(0.f,0.f,0.f,0.f);
  if (row < DPROJ) v = *(const float4*)(w + ((size_t)ly*DPROJ + row)*DIM + col);
  unsigned short hi[4], lo[4];
  const float* vp = (const float*)&v;
#pragma unroll
  for (int i = 0; i < 4; ++i) {
    hi[i] = f2bf(vp[i]);
    lo[i] = f2bf(vp[i] - bf2f(hi[i]));
  }
  *(uint2*)(wH + e) = *(const uint2*)hi;
  *(uint2*)(wL + e) = *(const uint2*)lo;
}

// ---------------------------------------------------------------- front MLP (writes h + hi/lo)
__global__ void __launch_bounds__(256) k_front(
    const float* __restrict__ x, const float* __restrict__ w1,
    const float* __restrict__ b1, const float* __restrict__ w2,
    const float* __restrict__ b2, const float* __restrict__ cls,
    float* __restrict__ h, unsigned short* __restrict__ hH,
    unsigned short* __restrict__ hL) {
  int t = threadIdx.x;
  if (blockIdx.x == BATCH*64) {              // cls rows
    if (t < DIM) {
      float cv = cls[t];
      unsigned short hi = f2bf(cv);
      unsigned short lo = f2bf(cv - bf2f(hi));
      for (int b = 0; b < BATCH; ++b) {
        h[((size_t)b*LH + LSEQ)*DIM + t] = cv;
        hH[((size_t)b*LHP + LSEQ)*DIM + t] = hi;
        hL[((size_t)b*LHP + LSEQ)*DIM + t] = lo;
      }
    }
    return;
  }
  int b = blockIdx.x >> 6;
  int c0 = (blockIdx.x & 63) * FTR;
  __shared__ float xs[(FTR+4)*CIN];
  __shared__ float w1s[DIM*17];
  __shared__ __align__(16) float h1s[FTR][DIM];
  __shared__ float part[FTR][DIM][2];
  for (int i = t; i < (FTR+4)*CIN; i += 256) {
    int row = c0 + i/3, ch = i - (i/3)*3;
    xs[i] = (row < TSEQ) ? x[(size_t)b*TSEQ*CIN + (size_t)row*CIN + ch] : 0.f;
  }
  for (int i = t; i < DIM*15; i += 256) {
    int j = i/15, k = i - j*15;
    w1s[j*17+k] = w1[i];
  }
  __syncthreads();
  {
    int j = t & 127, rh = t >> 7;
    float bias = b1[j];
    const float* wr = &w1s[j*17];
    for (int r = rh*16; r < rh*16+16; ++r) {
      float a = bias;
#pragma unroll
      for (int k = 0; k < 15; ++k) a += xs[r*3+k]*wr[k];
      h1s[r][j] = 0.5f*a*(1.f + erff(a*0.70710678118654752f));  // exact gelu
    }
  }
  __syncthreads();
  {
    int j = t & 127, hf = t >> 7;
    float4 wv[16];
    const float4* w2r = (const float4*)(w2 + (size_t)j*DIM + hf*64);
#pragma unroll
    for (int k4 = 0; k4 < 16; ++k4) wv[k4] = w2r[k4];
#pragma unroll 2
    for (int r = 0; r < FTR; ++r) {
      const float4* hr = (const float4*)&h1s[r][hf*64];
      float acc = 0.f;
#pragma unroll
      for (int k4 = 0; k4 < 16; ++k4) {
        float4 hv = hr[k4];
        acc += wv[k4].x*hv.x + wv[k4].y*hv.y + wv[k4].z*hv.z + wv[k4].w*hv.w;
      }
      part[r][j][hf] = acc;
    }
  }
  __syncthreads();
  if (t < DIM) {
    float bias = b2[t];
    for (int r = 0; r < FTR; ++r) {
      int l = c0 + r;
      if (l < LSEQ) {
        float val = part[r][t][0] + part[r][t][1] + bias;
        h[((size_t)b*LH + l)*DIM + t] = val;
        unsigned short hi = f2bf(val);
        hH[((size_t)b*LHP + l)*DIM + t] = hi;
        hL[((size_t)b*LHP + l)*DIM + t] = f2bf(val - bf2f(hi));
      }
    }
  }
}

// ---------------------------------------------------------------- in_proj via bf16x3 MFMA
// Error-compensated: C = Ah*Bh + Al*Bh + Ah*Bl (~fp32 accuracy, rel err ~2^-17).
// A-frag: h[m=lane&15][k=q*8+i]; B-frag: W[n=lane&15][k] (original [j][k] layout);
// D: col=lane&15 -> j, row=q*4+reg -> token (m89/m120 layouts).
__global__ void __launch_bounds__(256) k_inproj_mfma(
    const unsigned short* __restrict__ hH, const unsigned short* __restrict__ hL,
    const unsigned short* __restrict__ wH, const unsigned short* __restrict__ wL,
    const float* __restrict__ dtb, float* __restrict__ zx) {
  int b = blockIdx.x >> 5;
  int lb = blockIdx.x & 31;
  int wv = threadIdx.x >> 6, lane = threadIdx.x & 63;
  int l0 = lb*64 + wv*16;
  int m = lane & 15, q = lane >> 4;
  size_t hoff = ((size_t)b*LHP + (l0 + m))*DIM + q*8;
  bf16x8 ah[4], al[4];
#pragma unroll
  for (int kb = 0; kb < 4; ++kb) {
    ah[kb] = *(const bf16x8*)(hH + hoff + kb*32);
    al[kb] = *(const bf16x8*)(hL + hoff + kb*32);
  }
#pragma unroll 1
  for (int jt = 0; jt < 41; ++jt) {
    int j0 = jt*16;
    size_t woff = (size_t)(j0 + m)*DIM + q*8;
    bf16x8 bh[4], bl[4];
#pragma unroll
    for (int kb = 0; kb < 4; ++kb) {
      bh[kb] = *(const bf16x8*)(wH + woff + kb*32);
      bl[kb] = *(const bf16x8*)(wL + woff + kb*32);
    }
    f32x4 acc = {0.f, 0.f, 0.f, 0.f};
#pragma unroll
    for (int kb = 0; kb < 4; ++kb)
      acc = __builtin_amdgcn_mfma_f32_16x16x32_bf16(al[kb], bh[kb], acc, 0, 0, 0);
#pragma unroll
    for (int kb = 0; kb < 4; ++kb)
      acc = __builtin_amdgcn_mfma_f32_16x16x32_bf16(ah[kb], bl[kb], acc, 0, 0, 0);
#pragma unroll
    for (int kb = 0; kb < 4; ++kb)
      acc = __builtin_amdgcn_mfma_f32_16x16x32_bf16(ah[kb], bh[kb], acc, 0, 0, 0);
    int jj = j0 + m;                        // D col = lane&15
    if (jj < DPROJ) {
      bool isdt = (jj >= 640);
      float bias = isdt ? dtb[jj - 640] : 0.f;
#pragma unroll
      for (int r = 0; r < 4; ++r) {
        int tok = l0 + q*4 + r;             // D row = q*4 + reg
        if (tok < LH) {
          float v = acc[r];
          if (isdt) { v += bias; v = (v > 20.f) ? v : log1pf(__expf(v)); }
          zx[((size_t)b*LH + tok)*DPROJ + jj] = v;
        }
      }
    }
  }
}

// ---------------------------------------------------------------- causal dwconv + silu
// float4 over channels. R9 lesson: materialize once.
__global__ void k_conv(const float* __restrict__ zx, const float* __restrict__ cw,
                       const float* __restrict__ cb, float* __restrict__ xbc) {
  size_t idx = (size_t)blockIdx.x*blockDim.x + threadIdx.x;
  const size_t total = (size_t)BATCH*LH*(CONVD/4);
  if (idx >= total) return;
  int c4 = (int)(idx % (CONVD/4)) * 4;
  size_t bl = idx / (CONVD/4);
  int l = (int)(bl % LH); int b = (int)(bl / LH);
  float4 w0 = *(const float4*)(cw + (c4+0)*4);
  float4 w1 = *(const float4*)(cw + (c4+1)*4);
  float4 w2 = *(const float4*)(cw + (c4+2)*4);
  float4 w3 = *(const float4*)(cw + (c4+3)*4);
  float4 a = *(const float4*)(cb + c4);
#pragma unroll
  for (int k = 0; k < 4; ++k) {
    int tin = l - 3 + k;
    if (tin >= 0) {
      float4 v = *(const float4*)(zx + ((size_t)b*LH + tin)*DPROJ + DIN + c4);
      a.x += v.x * ((const float*)&w0)[k];
      a.y += v.y * ((const float*)&w1)[k];
      a.z += v.z * ((const float*)&w2)[k];
      a.w += v.w * ((const float*)&w3)[k];
    }
  }
  float4 o;
  o.x = siluf_(a.x); o.y = siluf_(a.y); o.z = siluf_(a.z); o.w = siluf_(a.w);
  *(float4*)(xbc + ((size_t)b*LH + l)*CONVD + c4) = o;
}

// ---------------------------------------------------------------- chunked SSD, phase A
__global__ void __launch_bounds__(256) k_chunk_state(
    const float* __restrict__ zx, const float* __restrict__ xbc,
    const float* __restrict__ A_log, float* __restrict__ G, float* __restrict__ dec) {
  int blk = blockIdx.x;
  int c = blk & (NCH-1), hd = (blk >> 5) & 3, b = blk >> 7;
  int t0 = c*QC;
  int tid = threadIdx.x;
  float A = -__expf(A_log[hd]);
  __shared__ float xs[QC*PDIM];
  __shared__ float Bs[QC*NSTATE];
  __shared__ float coef[QC];
  if (tid < 64) {
    int tg = t0 + tid;
    float dtv = (tg < LH) ? zx[((size_t)b*LH + tg)*DPROJ + 640 + hd] : 0.f;
    float s = dtv;
#pragma unroll
    for (int off = 1; off < 64; off <<= 1) {
      float u = __shfl_up(s, off);
      if (tid >= off) s += u;
    }
    float cq = __shfl(s, 63);
    coef[tid] = __expf(A*(cq - s)) * dtv;
    if (tid == 63) dec[blk] = __expf(A * s);
  }
  for (int i = tid; i < QC*64; i += 256) {
    int s = i >> 6, j = i & 63;
    int tg = t0 + s;
    float xv = 0.f, bv = 0.f;
    if (tg < LH) {
      size_t row = ((size_t)b*LH + tg)*CONVD;
      xv = xbc[row + hd*PDIM + j];
      bv = xbc[row + DIN + j];
    }
    xs[i] = xv; Bs[i] = bv;
  }
  __syncthreads();
  int n = tid >> 2, q = tid & 3;
  float4 acc[4];
#pragma unroll
  for (int i4 = 0; i4 < 4; ++i4) acc[i4] = make_float4(0.f,0.f,0.f,0.f);
  const float4* xs4 = (const float4*)xs;
#pragma unroll 4
  for (int s = 0; s < QC; ++s) {            // capped unroll: keep VGPRs < spill
    float cb_ = coef[s] * Bs[s*64 + n];
#pragma unroll
    for (int i4 = 0; i4 < 4; ++i4) {
      float4 xv = xs4[s*16 + q*4 + i4];
      acc[i4].x += cb_*xv.x; acc[i4].y += cb_*xv.y;
      acc[i4].z += cb_*xv.z; acc[i4].w += cb_*xv.w;
    }
  }
  float4* gp = (float4*)(G + (size_t)blk*4096 + n*64 + q*16);
#pragma unroll
  for (int i4 = 0; i4 < 4; ++i4) gp[i4] = acc[i4];
}

// ---------------------------------------------------------------- phase B: inter-chunk
__global__ void __launch_bounds__(256) k_combine(
    const float* __restrict__ G, const float* __restrict__ dec, float* __restrict__ Hin) {
  int bh = blockIdx.x >> 2, esp = blockIdx.x & 3;
  int e = esp*1024 + threadIdx.x*4;
  size_t base0 = (size_t)bh*NCH*4096 + e;
  float4 H = make_float4(0.f,0.f,0.f,0.f);
  float4 g = *(const float4*)(G + base0);
  float d = dec[bh*NCH];
  for (int c = 0; c < NCH; ++c) {
    float4 gn = make_float4(0.f,0.f,0.f,0.f); float dn = 0.f;
    if (c + 1 < NCH) {
      gn = *(const float4*)(G + base0 + (size_t)(c+1)*4096);
      dn = dec[bh*NCH + c + 1];
    }
    *(float4*)(Hin + base0 + (size_t)c*4096) = H;   // carry-in for chunk c
    H.x = H.x*d + g.x; H.y = H.y*d + g.y; H.z = H.z*d + g.z; H.w = H.w*d + g.w;
    g = gn; d = dn;
  }
}

// ---------------------------------------------------------------- phase C: chunk output
__global__ void __launch_bounds__(256) k_chunk_out(
    const float* __restrict__ zx, const float* __restrict__ xbc,
    const float* __restrict__ A_log, const float* __restrict__ Hin,
    float* __restrict__ y) {
  int blk = blockIdx.x;
  int c = blk & (NCH-1), hd = (blk >> 5) & 3, b = blk >> 7;
  int t0 = c*QC;
  int tid = threadIdx.x;
  int tr = tid >> 4, tc = tid & 15;
  float A = -__expf(A_log[hd]);
  __shared__ __align__(16) float SA[QC*LDP];
  __shared__ __align__(16) float SB[QC*LDP];
  __shared__ __align__(16) float SC[QC*LDP];
  __shared__ float cum[QC], dts[QC], pref[QC];
  if (tid < 64) {
    int tg = t0 + tid;
    float dtv = (tg < LH) ? zx[((size_t)b*LH + tg)*DPROJ + 640 + hd] : 0.f;
    float s = dtv;
#pragma unroll
    for (int off = 1; off < 64; off <<= 1) {
      float u = __shfl_up(s, off);
      if (tid >= off) s += u;
    }
    dts[tid] = dtv; cum[tid] = s; pref[tid] = __expf(A*s);
  }
  for (int i = tid; i < QC*64; i += 256) {
    int s = i >> 6, j = i & 63;
    int tg = t0 + s;
    float bv = 0.f, cv = 0.f;
    if (tg < LH) {
      size_t row = ((size_t)b*LH + tg)*CONVD;
      bv = xbc[row + DIN + j];
      cv = xbc[row + DIN + NSTATE + j];
    }
    SA[s*LDP + j] = bv; SB[s*LDP + j] = cv;
  }
  __syncthreads();
  // ---- S = C B^T
  float S[4][4];
#pragma unroll
  for (int j = 0; j < 4; ++j)
#pragma unroll
    for (int i = 0; i < 4; ++i) S[j][i] = 0.f;
  const float4* SA4 = (const float4*)SA;
  const float4* SB4 = (const float4*)SB;
#pragma unroll 2
  for (int n4 = 0; n4 < 16; ++n4) {
    float4 cv[4], bv[4];
#pragma unroll
    for (int j = 0; j < 4; ++j) cv[j] = SB4[(tr + 16*j)*(LDP/4) + n4];
#pragma unroll
    for (int i = 0; i < 4; ++i) bv[i] = SA4[(tc + 16*i)*(LDP/4) + n4];
#pragma unroll
    for (int j = 0; j < 4; ++j)
#pragma unroll
      for (int i = 0; i < 4; ++i)
        S[j][i] += cv[j].x*bv[i].x + cv[j].y*bv[i].y + cv[j].z*bv[i].z + cv[j].w*bv[i].w;
  }
  __syncthreads();
  // ---- masked decay -> M in SC; reload X into SA
#pragma unroll
  for (int j = 0; j < 4; ++j) {
    int t = tr + 16*j;
#pragma unroll
    for (int i = 0; i < 4; ++i) {
      int s = tc + 16*i;
      float m = 0.f;
      if (s <= t) m = S[j][i] * __expf(A*(cum[t] - cum[s])) * dts[s];
      SC[t*LDP + s] = m;
    }
  }
  for (int i = tid; i < QC*64; i += 256) {
    int s = i >> 6, j = i & 63;
    int tg = t0 + s;
    SA[s*LDP + j] = (tg < LH) ? xbc[((size_t)b*LH + tg)*CONVD + hd*PDIM + j] : 0.f;
  }
  __syncthreads();
  // ---- Y1 = M X
  float4 y1[4];
#pragma unroll
  for (int j = 0; j < 4; ++j) y1[j] = make_float4(0.f,0.f,0.f,0.f);
  const float4* SC4 = (const float4*)SC;
#pragma unroll 2
  for (int s4 = 0; s4 < 16; ++s4) {
    float4 mj[4], xk[4];
#pragma unroll
    for (int j = 0; j < 4; ++j) mj[j] = SC4[(tr + 16*j)*(LDP/4) + s4];
#pragma unroll
    for (int k = 0; k < 4; ++k) xk[k] = SA4[(s4*4 + k)*(LDP/4) + tc];
#pragma unroll
    for (int j = 0; j < 4; ++j) {
      y1[j].x += mj[j].x*xk[0].x + mj[j].y*xk[1].x + mj[j].z*xk[2].x + mj[j].w*xk[3].x;
      y1[j].y += mj[j].x*xk[0].y + mj[j].y*xk[1].y + mj[j].z*xk[2].y + mj[j].w*xk[3].y;
      y1[j].z += mj[j].x*xk[0].z + mj[j].y*xk[1].z + mj[j].z*xk[2].z + mj[j].w*xk[3].z;
      y1[j].w += mj[j].x*xk[0].w + mj[j].y*xk[1].w + mj[j].z*xk[2].w + mj[j].w*xk[3].w;
    }
  }
  __syncthreads();
  size_t hbase = (size_t)blk*4096;
  for (int i = tid; i < 4096; i += 256) SC[(i >> 6)*LDP + (i & 63)] = Hin[hbase + i];
  __syncthreads();
  // ---- Y2 = C H_in^T
  float4 y2[4];
#pragma unroll
  for (int j = 0; j < 4; ++j) y2[j] = make_float4(0.f,0.f,0.f,0.f);
#pragma unroll 2
  for (int n4 = 0; n4 < 16; ++n4) {
    float4 cj[4], hk[4];
#pragma unroll
    for (int j = 0; j < 4; ++j) cj[j] = SB4[(tr + 16*j)*(LDP/4) + n4];
#pragma unroll
    for (int k = 0; k < 4; ++k) hk[k] = SC4[(n4*4 + k)*(LDP/4) + tc];
#pragma unroll
    for (int j = 0; j < 4; ++j) {
      y2[j].x += cj[j].x*hk[0].x + cj[j].y*hk[1].x + cj[j].z*hk[2].x + cj[j].w*hk[3].x;
      y2[j].y += cj[j].x*hk[0].y + cj[j].y*hk[1].y + cj[j].z*hk[2].y + cj[j].w*hk[3].y;
      y2[j].z += cj[j].x*hk[0].z + cj[j].y*hk[1].z + cj[j].z*hk[2].z + cj[j].w*hk[3].z;
      y2[j].w += cj[j].x*hk[0].w + cj[j].y*hk[1].w + cj[j].z*hk[2].w + cj[j].w*hk[3].w;
    }
  }
#pragma unroll
  for (int j = 0; j < 4; ++j) {
    int t = tr + 16*j, tg = t0 + t;
    if (tg < LH) {
      float pr = pref[t];
      float4 o;
      o.x = y1[j].x + pr*y2[j].x;
      o.y = y1[j].y + pr*y2[j].y;
      o.z = y1[j].z + pr*y2[j].z;
      o.w = y1[j].w + pr*y2[j].w;
      *(float4*)(y + ((size_t)b*LH + tg)*DIN + hd*PDIM + tc*4) = o;
    }
  }
}

// ---------------------------------------------------------------- gate + rmsnorm + out_proj
// Writes h (fp32) + hi/lo bf16 — casts fused.
#define TR5 8
__global__ void __launch_bounds__(256) k_out(
    const float* __restrict__ y, const float* __restrict__ xbc,
    const float* __restrict__ zx, const float* __restrict__ Dh,
    const float* __restrict__ nw, const float* __restrict__ owT,
    float* __restrict__ h, unsigned short* __restrict__ hH,
    unsigned short* __restrict__ hL) {
  const int nblk_l = 256;
  int b = blockIdx.x / nblk_l;
  int l0 = (blockIdx.x % nblk_l) * TR5;
  int t = threadIdx.x;
  __shared__ __align__(16) float yv[TR5][DIN];
  __shared__ float part[4][TR5][DIM];
  __shared__ float red[TR5][4];
  __shared__ float rs[TR5];
  int c = t;
  int hd = c >> 6;
  float dcoef = Dh[hd];
  float nwc = nw[c];
  float v[TR5];
#pragma unroll
  for (int r = 0; r < TR5; ++r) {
    int l = l0 + r;
    float val = 0.f;
    if (l < LH) {
      size_t row = (size_t)b*LH + l;
      float ys = y[row*DIN + c];
      float xh = xbc[row*CONVD + c];
      float z  = zx[row*DPROJ + c];
      val = (ys + dcoef*xh) * siluf_(z);
    }
    v[r] = val;
  }
  int wave = t >> 6, lane = t & 63;
#pragma unroll
  for (int r = 0; r < TR5; ++r) {
    float sq = v[r]*v[r];
    for (int off = 32; off > 0; off >>= 1) sq += __shfl_down(sq, off);
    if (lane == 0) red[r][wave] = sq;
  }
  __syncthreads();
  if (t < TR5) {
    float sm = red[t][0]+red[t][1]+red[t][2]+red[t][3];
    rs[t] = rsqrtf(sm/(float)DIN + 1e-5f);
  }
  __syncthreads();
#pragma unroll
  for (int r = 0; r < TR5; ++r) yv[r][c] = v[r] * rs[r] * nwc;
  __syncthreads();
  int jp = t & 63, q = t >> 6;
  int j0 = jp*2;
  float acc[2][TR5];
#pragma unroll
  for (int jj = 0; jj < 2; ++jj)
#pragma unroll
    for (int r = 0; r < TR5; ++r) acc[jj][r] = 0.f;
  const float* wtb = owT + (size_t)q*64*DIM + j0;
#pragma unroll 2
  for (int k4 = 0; k4 < 16; ++k4) {
    float2 w0 = *(const float2*)(wtb + (k4*4+0)*DIM);
    float2 w1 = *(const float2*)(wtb + (k4*4+1)*DIM);
    float2 w2_ = *(const float2*)(wtb + (k4*4+2)*DIM);
    float2 w3 = *(const float2*)(wtb + (k4*4+3)*DIM);
#pragma unroll
    for (int r = 0; r < TR5; ++r) {
      float4 hv = ((const float4*)&yv[r][q*64])[k4];
      acc[0][r] += w0.x*hv.x + w1.x*hv.y + w2_.x*hv.z + w3.x*hv.w;
      acc[1][r] += w0.y*hv.x + w1.y*hv.y + w2_.y*hv.z + w3.y*hv.w;
    }
  }
#pragma unroll
  for (int r = 0; r < TR5; ++r) {
    part[q][r][j0]   = acc[0][r];
    part[q][r][j0+1] = acc[1][r];
  }
  __syncthreads();
  if (t < DIM) {
#pragma unroll 2
    for (int r = 0; r < TR5; ++r) {
      int l = l0 + r;
      if (l < LH) {
        float val = part[0][r][t] + part[1][r][t] + part[2][r][t] + part[3][r][t];
        h[((size_t)b*LH + l)*DIM + t] = val;
        unsigned short hi = f2bf(val);
        hH[((size_t)b*LHP + l)*DIM + t] = hi;
        hL[((size_t)b*LHP + l)*DIM + t] = f2bf(val - bf2f(hi));
      }
    }
  }
}

// ---------------------------------------------------------------- final LN + head
__global__ void k_head(const float* __restrict__ h, const float* __restrict__ lnw,
                       const float* __restrict__ lnb, const float* __restrict__ hw,
                       const float* __restrict__ hb, float* __restrict__ out) {
  int b = blockIdx.x; int t = threadIdx.x;
  __shared__ float red[2];
  int wave = t >> 6, lane = t & 63;
  float v = h[((size_t)b*LH + LSEQ)*DIM + t];
  float s = v;
  for (int off = 32; off > 0; off >>= 1) s += __shfl_down(s, off);
  if (lane == 0) red[wave] = s;
  __syncthreads();
  float mean = (red[0]+red[1]) / (float)DIM;
  __syncthreads();
  float d = v - mean; float sq = d*d;
  for (int off = 32; off > 0; off >>= 1) sq += __shfl_down(sq, off);
  if (lane == 0) red[wave] = sq;
  __syncthreads();
  float var = (red[0]+red[1]) / (float)DIM;
  float cn = d*rsqrtf(var + 1e-5f)*lnw[t] + lnb[t];
  float dot = cn*hw[t];
  __syncthreads();
  for (int off = 32; off > 0; off >>= 1) dot += __shfl_down(dot, off);
  if (lane == 0) red[wave] = dot;
  __syncthreads();
  if (t == 0) out[b] = red[0]+red[1] + hb[0];
}

// ---------------------------------------------------------------- h -> d_out copy
__global__ void k_copy(const float* __restrict__ src, float* __restrict__ dst, long n4) {
  long i = (long)blockIdx.x*blockDim.x + threadIdx.x;
  if (i < n4) ((float4*)dst)[i] = ((const float4*)src)[i];
}

extern "C" void kernel_launch(void* const* d_in, const int* in_sizes, int n_in,
                              void* d_out, int out_size, void* d_ws, size_t ws_size,
                              hipStream_t stream) {
  const float* x     = (const float*)d_in[0];
  const float* w1    = (const float*)d_in[1];
  const float* b1    = (const float*)d_in[2];
  const float* w2    = (const float*)d_in[3];
  const float* b2    = (const float*)d_in[4];
  const float* cls   = (const float*)d_in[5];
  const float* inw   = (const float*)d_in[6];   // (4, 644, 128)
  const float* cw    = (const float*)d_in[7];   // (4, 384, 4)
  const float* cb    = (const float*)d_in[8];   // (4, 384)
  const float* dtb   = (const float*)d_in[9];   // (4, 4)
  const float* Alog  = (const float*)d_in[10];  // (4, 4)
  const float* Dh    = (const float*)d_in[11];  // (4, 4)
  const float* nw    = (const float*)d_in[12];  // (4, 256)
  const float* ow    = (const float*)d_in[13];  // (4, 128, 256)
  const float* lnw   = (const float*)d_in[14];
  const float* lnb   = (const float*)d_in[15];
  const float* hw    = (const float*)d_in[16];
  const float* hb    = (const float*)d_in[17];

  float* ws   = (float*)d_ws;
  float* hbuf = ws;                                   // 2,094,080
  float* zx   = hbuf + (size_t)BATCH*LH*DIM;          // 10,535,840
  float* xbc  = zx   + (size_t)BATCH*LH*DPROJ;        // 6,282,240
  float* ybuf = xbc  + (size_t)BATCH*LH*CONVD;        // 4,194,304 (G aliases ybuf)
  float* G    = ybuf;
  float* Hin  = ybuf + 4194304;                       // 4,194,304
  float* dec  = Hin  + 4194304;                       // 1,024
  float* owT  = dec  + 1024;                          // 131,072
  unsigned short* hH = (unsigned short*)(owT + 131072);    // 8*2048*128 u16
  unsigned short* hL = hH + (size_t)BATCH*LHP*DIM;         // 8*2048*128 u16
  unsigned short* wH = hL + (size_t)BATCH*LHP*DIM;         // 4*656*128 u16
  unsigned short* wL = wH + (size_t)DEPTH*DPROJP*DIM;      // 4*656*128 u16
  // total ~29.87M floats = 119.5 MiB

  k_cast_w<<<(DEPTH*DPROJP*DIM/4 + 255)/256, 256, 0, stream>>>(inw, wH, wL);
  k_transpose<<<dim3(4,2,4), 256, 0, stream>>>(ow, owT, DIM, DIN);

  k_front<<<BATCH*64 + 1, 256, 0, stream>>>(x, w1, b1, w2, b2, cls, hbuf, hH, hL);

  for (int i = 0; i < DEPTH; ++i) {
    k_inproj_mfma<<<BATCH*32, 256, 0, stream>>>(
        hH, hL, wH + (size_t)i*DPROJP*DIM, wL + (size_t)i*DPROJP*DIM,
        dtb + i*NH, zx);
    {
      long total = (long)BATCH*LH*(CONVD/4);
      k_conv<<<(int)((total + 255)/256), 256, 0, stream>>>(
          zx, cw + (size_t)i*CONVD*4, cb + (size_t)i*CONVD, xbc);
    }
    k_chunk_state<<<BATCH*NH*NCH, 256, 0, stream>>>(zx, xbc, Alog + i*NH, G, dec);
    k_combine<<<BATCH*NH*4, 256, 0, stream>>>(G, dec, Hin);
    k_chunk_out<<<BATCH*NH*NCH, 256, 0, stream>>>(zx, xbc, Alog + i*NH, Hin, ybuf);
    k_out<<<BATCH*256, 256, 0, stream>>>(
        ybuf, xbc, zx, Dh + i*NH, nw + (size_t)i*DIN, owT + (size_t)i*DIM*DIN,
        hbuf, hH, hL);
  }

  k_head<<<BATCH, 128, 0, stream>>>(hbuf, lnw, lnb, hw, hb, (float*)d_out);
  {
    long n4 = (long)BATCH*LH*DIM/4;
    k_copy<<<(int)((n4 + 255)/256), 256, 0, stream>>>(hbuf, (float*)d_out + 8, n4);
  }
}

// Round 14
// 747.941 us; speedup vs baseline: 1.1401x; 1.1401x over previous
//
#include <hip/hip_runtime.h>
#include <math.h>

// Shapes (fixed by setup_inputs)
#define BATCH 8
#define TSEQ 2048
#define CIN 3
#define WIN 5
#define LSEQ 2044          // T - WIN + 1
#define LH 2045            // LSEQ + 1 (cls token appended)
#define LHP 2048           // padded token rows for bf16 h buffers
#define DIM 128
#define DEPTH 4
#define DIN 256            // d_inner
#define NH 4               // heads
#define PDIM 64            // headdim
#define NSTATE 64          // d_state
#define CONVD 384          // d_inner + 2*d_state
#define DPROJ 644          // 2*d_inner + 2*d_state + nheads
#define NJT 41             // j-tiles of 16 (41*16 = 656 >= 644)
#define QC 64              // chunk length
#define NCH 32             // number of chunks
#define LDP 68             // padded LDS row stride
#define FTR 32             // tokens per k_front block

typedef __attribute__((ext_vector_type(8))) short bf16x8;
typedef __attribute__((ext_vector_type(4))) float f32x4;

__device__ __forceinline__ float sigmoidf_(float x){ return 1.f/(1.f+__expf(-x)); }
__device__ __forceinline__ float siluf_(float x){ return x*sigmoidf_(x); }
__device__ __forceinline__ unsigned short f2bf(float f){   // RNE fp32->bf16
  unsigned int u = __float_as_uint(f);
  return (unsigned short)((u + 0x7FFFu + ((u >> 16) & 1u)) >> 16);
}
__device__ __forceinline__ float bf2f(unsigned short u){
  return __uint_as_float(((unsigned int)u) << 16);
}

// ---------------------------------------------------------------- weight transpose (ow only)
__global__ void __launch_bounds__(256) k_transpose(
    const float* __restrict__ src, float* __restrict__ dst, int R, int C) {
  __shared__ float tile[64][65];
  const float* s = src + (size_t)blockIdx.z*R*C;
  float* d = dst + (size_t)blockIdx.z*R*C;
  int r0 = blockIdx.y*64, c0 = blockIdx.x*64;
  int tx = threadIdx.x & 63, ty = threadIdx.x >> 6;
  for (int rr = ty; rr < 64; rr += 4) {
    int r = r0 + rr, c = c0 + tx;
    if (r < R && c < C) tile[rr][tx] = s[(size_t)r*C + c];
  }
  __syncthreads();
  for (int cc = ty; cc < 64; cc += 4) {
    int c = c0 + cc, r = r0 + tx;
    if (c < C && r < R) d[(size_t)c*R + r] = tile[tx][cc];
  }
}

// inw -> MFMA-fragment-order bf16 hi/lo: wS[layer][jt][kb][lane][8].
// Lane (m=lane&15, q=lane>>4) of tile jt needs W[jt*16+m][kb*32+q*8 .. +8].
// Fragment loads in the GEMM become lane-contiguous (1KB/instr, coalesced).
__global__ void __launch_bounds__(256) k_cast_w(
    const float* __restrict__ w, unsigned short* __restrict__ wH,
    unsigned short* __restrict__ wL) {
  int gid = blockIdx.x*256 + threadIdx.x;     // [ly][jt][kb][lane]
  if (gid >= DEPTH*NJT*4*64) return;
  int lane = gid & 63;
  int kb = (gid >> 6) & 3;
  int jt = (gid >> 8) % NJT;
  int ly = gid / (NJT*4*64);
  int m = lane & 15, q = lane >> 4;
  int j = jt*16 + m;
  int k = kb*32 + q*8;
  unsigned short hi[8], lo[8];
  if (j < DPROJ) {
    const float* src = w + ((size_t)ly*DPROJ + j)*DIM + k;
#pragma unroll
    for (int i = 0; i < 8; ++i) {
      float v = src[i];
      hi[i] = f2bf(v);
      lo[i] = f2bf(v - bf2f(hi[i]));
    }
  } else {
#pragma unroll
    for (int i = 0; i < 8; ++i) { hi[i] = 0; lo[i] = 0; }
  }
  size_t dst = (size_t)gid*8;
  *(uint4*)(wH + dst) = *(const uint4*)hi;
  *(uint4*)(wL + dst) = *(const uint4*)lo;
}

// ---------------------------------------------------------------- front MLP (writes h + hi/lo)
__global__ void __launch_bounds__(256) k_front(
    const float* __restrict__ x, const float* __restrict__ w1,
    const float* __restrict__ b1, const float* __restrict__ w2,
    const float* __restrict__ b2, const float* __restrict__ cls,
    float* __restrict__ h, unsigned short* __restrict__ hH,
    unsigned short* __restrict__ hL) {
  int t = threadIdx.x;
  if (blockIdx.x == BATCH*64) {              // cls rows
    if (t < DIM) {
      float cv = cls[t];
      unsigned short hi = f2bf(cv);
      unsigned short lo = f2bf(cv - bf2f(hi));
      for (int b = 0; b < BATCH; ++b) {
        h[((size_t)b*LH + LSEQ)*DIM + t] = cv;
        hH[((size_t)b*LHP + LSEQ)*DIM + t] = hi;
        hL[((size_t)b*LHP + LSEQ)*DIM + t] = lo;
      }
    }
    return;
  }
  int b = blockIdx.x >> 6;
  int c0 = (blockIdx.x & 63) * FTR;
  __shared__ float xs[(FTR+4)*CIN];
  __shared__ float w1s[DIM*17];
  __shared__ __align__(16) float h1s[FTR][DIM];
  __shared__ float part[FTR][DIM][2];
  for (int i = t; i < (FTR+4)*CIN; i += 256) {
    int row = c0 + i/3, ch = i - (i/3)*3;
    xs[i] = (row < TSEQ) ? x[(size_t)b*TSEQ*CIN + (size_t)row*CIN + ch] : 0.f;
  }
  for (int i = t; i < DIM*15; i += 256) {
    int j = i/15, k = i - j*15;
    w1s[j*17+k] = w1[i];
  }
  __syncthreads();
  {
    int j = t & 127, rh = t >> 7;
    float bias = b1[j];
    const float* wr = &w1s[j*17];
    for (int r = rh*16; r < rh*16+16; ++r) {
      float a = bias;
#pragma unroll
      for (int k = 0; k < 15; ++k) a += xs[r*3+k]*wr[k];
      h1s[r][j] = 0.5f*a*(1.f + erff(a*0.70710678118654752f));  // exact gelu
    }
  }
  __syncthreads();
  {
    int j = t & 127, hf = t >> 7;
    float4 wv[16];
    const float4* w2r = (const float4*)(w2 + (size_t)j*DIM + hf*64);
#pragma unroll
    for (int k4 = 0; k4 < 16; ++k4) wv[k4] = w2r[k4];
#pragma unroll 2
    for (int r = 0; r < FTR; ++r) {
      const float4* hr = (const float4*)&h1s[r][hf*64];
      float acc = 0.f;
#pragma unroll
      for (int k4 = 0; k4 < 16; ++k4) {
        float4 hv = hr[k4];
        acc += wv[k4].x*hv.x + wv[k4].y*hv.y + wv[k4].z*hv.z + wv[k4].w*hv.w;
      }
      part[r][j][hf] = acc;
    }
  }
  __syncthreads();
  if (t < DIM) {
    float bias = b2[t];
    for (int r = 0; r < FTR; ++r) {
      int l = c0 + r;
      if (l < LSEQ) {
        float val = part[r][t][0] + part[r][t][1] + bias;
        h[((size_t)b*LH + l)*DIM + t] = val;
        unsigned short hi = f2bf(val);
        hH[((size_t)b*LHP + l)*DIM + t] = hi;
        hL[((size_t)b*LHP + l)*DIM + t] = f2bf(val - bf2f(hi));
      }
    }
  }
}

// ---------------------------------------------------------------- in_proj via bf16x3 MFMA
// Error-compensated: C = Al*Bh + Ah*Bl + Ah*Bh (~fp32, rel err ~2^-17).
// Weights pre-swizzled (k_cast_w) -> fragment loads coalesced. Grid split over
// j-halves: 512 blocks = 2 blocks/CU for latency hiding (R13: 1 block/CU, 5% util).
__global__ void __launch_bounds__(256) k_inproj_mfma(
    const unsigned short* __restrict__ hH, const unsigned short* __restrict__ hL,
    const unsigned short* __restrict__ wH, const unsigned short* __restrict__ wL,
    const float* __restrict__ dtb, float* __restrict__ zx) {
  int b = blockIdx.x >> 6;
  int r = blockIdx.x & 63;
  int lb = r >> 1, jh = r & 1;
  int wv = threadIdx.x >> 6, lane = threadIdx.x & 63;
  int l0 = lb*64 + wv*16;
  int m = lane & 15, q = lane >> 4;
  size_t hoff = ((size_t)b*LHP + (l0 + m))*DIM + q*8;
  bf16x8 ah[4], al[4];
#pragma unroll
  for (int kb = 0; kb < 4; ++kb) {
    ah[kb] = *(const bf16x8*)(hH + hoff + kb*32);
    al[kb] = *(const bf16x8*)(hL + hoff + kb*32);
  }
  int jt0 = jh ? 21 : 0, jtn = jh ? NJT : 21;
#pragma unroll 2
  for (int jt = jt0; jt < jtn; ++jt) {
    size_t woff = (((size_t)jt*4)*64 + lane)*8;
    bf16x8 bh[4], bl[4];
#pragma unroll
    for (int kb = 0; kb < 4; ++kb) {
      bh[kb] = *(const bf16x8*)(wH + woff + (size_t)kb*64*8);  // coalesced: lane*16B
      bl[kb] = *(const bf16x8*)(wL + woff + (size_t)kb*64*8);
    }
    f32x4 acc = {0.f, 0.f, 0.f, 0.f};
#pragma unroll
    for (int kb = 0; kb < 4; ++kb)
      acc = __builtin_amdgcn_mfma_f32_16x16x32_bf16(al[kb], bh[kb], acc, 0, 0, 0);
#pragma unroll
    for (int kb = 0; kb < 4; ++kb)
      acc = __builtin_amdgcn_mfma_f32_16x16x32_bf16(ah[kb], bl[kb], acc, 0, 0, 0);
#pragma unroll
    for (int kb = 0; kb < 4; ++kb)
      acc = __builtin_amdgcn_mfma_f32_16x16x32_bf16(ah[kb], bh[kb], acc, 0, 0, 0);
    int jj = jt*16 + m;                     // D col = lane&15
    if (jj < DPROJ) {
      bool isdt = (jj >= 640);
      float bias = isdt ? dtb[jj - 640] : 0.f;
#pragma unroll
      for (int rr = 0; rr < 4; ++rr) {
        int tok = l0 + q*4 + rr;            // D row = q*4 + reg
        if (tok < LH) {
          float v = acc[rr];
          if (isdt) { v += bias; v = (v > 20.f) ? v : log1pf(__expf(v)); }
          zx[((size_t)b*LH + tok)*DPROJ + jj] = v;
        }
      }
    }
  }
}

// ---------------------------------------------------------------- causal dwconv + silu
// float4 over channels. R9 lesson: materialize once.
__global__ void k_conv(const float* __restrict__ zx, const float* __restrict__ cw,
                       const float* __restrict__ cb, float* __restrict__ xbc) {
  size_t idx = (size_t)blockIdx.x*blockDim.x + threadIdx.x;
  const size_t total = (size_t)BATCH*LH*(CONVD/4);
  if (idx >= total) return;
  int c4 = (int)(idx % (CONVD/4)) * 4;
  size_t bl = idx / (CONVD/4);
  int l = (int)(bl % LH); int b = (int)(bl / LH);
  float4 w0 = *(const float4*)(cw + (c4+0)*4);
  float4 w1 = *(const float4*)(cw + (c4+1)*4);
  float4 w2 = *(const float4*)(cw + (c4+2)*4);
  float4 w3 = *(const float4*)(cw + (c4+3)*4);
  float4 a = *(const float4*)(cb + c4);
#pragma unroll
  for (int k = 0; k < 4; ++k) {
    int tin = l - 3 + k;
    if (tin >= 0) {
      float4 v = *(const float4*)(zx + ((size_t)b*LH + tin)*DPROJ + DIN + c4);
      a.x += v.x * ((const float*)&w0)[k];
      a.y += v.y * ((const float*)&w1)[k];
      a.z += v.z * ((const float*)&w2)[k];
      a.w += v.w * ((const float*)&w3)[k];
    }
  }
  float4 o;
  o.x = siluf_(a.x); o.y = siluf_(a.y); o.z = siluf_(a.z); o.w = siluf_(a.w);
  *(float4*)(xbc + ((size_t)b*LH + l)*CONVD + c4) = o;
}

// ---------------------------------------------------------------- chunked SSD, phase A
__global__ void __launch_bounds__(256) k_chunk_state(
    const float* __restrict__ zx, const float* __restrict__ xbc,
    const float* __restrict__ A_log, float* __restrict__ G, float* __restrict__ dec) {
  int blk = blockIdx.x;
  int c = blk & (NCH-1), hd = (blk >> 5) & 3, b = blk >> 7;
  int t0 = c*QC;
  int tid = threadIdx.x;
  float A = -__expf(A_log[hd]);
  __shared__ float xs[QC*PDIM];
  __shared__ float Bs[QC*NSTATE];
  __shared__ float coef[QC];
  if (tid < 64) {
    int tg = t0 + tid;
    float dtv = (tg < LH) ? zx[((size_t)b*LH + tg)*DPROJ + 640 + hd] : 0.f;
    float s = dtv;
#pragma unroll
    for (int off = 1; off < 64; off <<= 1) {
      float u = __shfl_up(s, off);
      if (tid >= off) s += u;
    }
    float cq = __shfl(s, 63);
    coef[tid] = __expf(A*(cq - s)) * dtv;
    if (tid == 63) dec[blk] = __expf(A * s);
  }
  for (int i = tid; i < QC*64; i += 256) {
    int s = i >> 6, j = i & 63;
    int tg = t0 + s;
    float xv = 0.f, bv = 0.f;
    if (tg < LH) {
      size_t row = ((size_t)b*LH + tg)*CONVD;
      xv = xbc[row + hd*PDIM + j];
      bv = xbc[row + DIN + j];
    }
    xs[i] = xv; Bs[i] = bv;
  }
  __syncthreads();
  int n = tid >> 2, q = tid & 3;
  float4 acc[4];
#pragma unroll
  for (int i4 = 0; i4 < 4; ++i4) acc[i4] = make_float4(0.f,0.f,0.f,0.f);
  const float4* xs4 = (const float4*)xs;
#pragma unroll 4
  for (int s = 0; s < QC; ++s) {            // capped unroll: keep VGPRs < spill
    float cb_ = coef[s] * Bs[s*64 + n];
#pragma unroll
    for (int i4 = 0; i4 < 4; ++i4) {
      float4 xv = xs4[s*16 + q*4 + i4];
      acc[i4].x += cb_*xv.x; acc[i4].y += cb_*xv.y;
      acc[i4].z += cb_*xv.z; acc[i4].w += cb_*xv.w;
    }
  }
  float4* gp = (float4*)(G + (size_t)blk*4096 + n*64 + q*16);
#pragma unroll
  for (int i4 = 0; i4 < 4; ++i4) gp[i4] = acc[i4];
}

// ---------------------------------------------------------------- phase B: inter-chunk
__global__ void __launch_bounds__(256) k_combine(
    const float* __restrict__ G, const float* __restrict__ dec, float* __restrict__ Hin) {
  int bh = blockIdx.x >> 2, esp = blockIdx.x & 3;
  int e = esp*1024 + threadIdx.x*4;
  size_t base0 = (size_t)bh*NCH*4096 + e;
  float4 H = make_float4(0.f,0.f,0.f,0.f);
  float4 g = *(const float4*)(G + base0);
  float d = dec[bh*NCH];
  for (int c = 0; c < NCH; ++c) {
    float4 gn = make_float4(0.f,0.f,0.f,0.f); float dn = 0.f;
    if (c + 1 < NCH) {
      gn = *(const float4*)(G + base0 + (size_t)(c+1)*4096);
      dn = dec[bh*NCH + c + 1];
    }
    *(float4*)(Hin + base0 + (size_t)c*4096) = H;   // carry-in for chunk c
    H.x = H.x*d + g.x; H.y = H.y*d + g.y; H.z = H.z*d + g.z; H.w = H.w*d + g.w;
    g = gn; d = dn;
  }
}

// ---------------------------------------------------------------- phase C: chunk output
__global__ void __launch_bounds__(256) k_chunk_out(
    const float* __restrict__ zx, const float* __restrict__ xbc,
    const float* __restrict__ A_log, const float* __restrict__ Hin,
    float* __restrict__ y) {
  int blk = blockIdx.x;
  int c = blk & (NCH-1), hd = (blk >> 5) & 3, b = blk >> 7;
  int t0 = c*QC;
  int tid = threadIdx.x;
  int tr = tid >> 4, tc = tid & 15;
  float A = -__expf(A_log[hd]);
  __shared__ __align__(16) float SA[QC*LDP];
  __shared__ __align__(16) float SB[QC*LDP];
  __shared__ __align__(16) float SC[QC*LDP];
  __shared__ float cum[QC], dts[QC], pref[QC];
  if (tid < 64) {
    int tg = t0 + tid;
    float dtv = (tg < LH) ? zx[((size_t)b*LH + tg)*DPROJ + 640 + hd] : 0.f;
    float s = dtv;
#pragma unroll
    for (int off = 1; off < 64; off <<= 1) {
      float u = __shfl_up(s, off);
      if (tid >= off) s += u;
    }
    dts[tid] = dtv; cum[tid] = s; pref[tid] = __expf(A*s);
  }
  for (int i = tid; i < QC*64; i += 256) {
    int s = i >> 6, j = i & 63;
    int tg = t0 + s;
    float bv = 0.f, cv = 0.f;
    if (tg < LH) {
      size_t row = ((size_t)b*LH + tg)*CONVD;
      bv = xbc[row + DIN + j];
      cv = xbc[row + DIN + NSTATE + j];
    }
    SA[s*LDP + j] = bv; SB[s*LDP + j] = cv;
  }
  __syncthreads();
  // ---- S = C B^T
  float S[4][4];
#pragma unroll
  for (int j = 0; j < 4; ++j)
#pragma unroll
    for (int i = 0; i < 4; ++i) S[j][i] = 0.f;
  const float4* SA4 = (const float4*)SA;
  const float4* SB4 = (const float4*)SB;
#pragma unroll 2
  for (int n4 = 0; n4 < 16; ++n4) {
    float4 cv[4], bv[4];
#pragma unroll
    for (int j = 0; j < 4; ++j) cv[j] = SB4[(tr + 16*j)*(LDP/4) + n4];
#pragma unroll
    for (int i = 0; i < 4; ++i) bv[i] = SA4[(tc + 16*i)*(LDP/4) + n4];
#pragma unroll
    for (int j = 0; j < 4; ++j)
#pragma unroll
      for (int i = 0; i < 4; ++i)
        S[j][i] += cv[j].x*bv[i].x + cv[j].y*bv[i].y + cv[j].z*bv[i].z + cv[j].w*bv[i].w;
  }
  __syncthreads();
  // ---- masked decay -> M in SC; reload X into SA
#pragma unroll
  for (int j = 0; j < 4; ++j) {
    int t = tr + 16*j;
#pragma unroll
    for (int i = 0; i < 4; ++i) {
      int s = tc + 16*i;
      float m = 0.f;
      if (s <= t) m = S[j][i] * __expf(A*(cum[t] - cum[s])) * dts[s];
      SC[t*LDP + s] = m;
    }
  }
  for (int i = tid; i < QC*64; i += 256) {
    int s = i >> 6, j = i & 63;
    int tg = t0 + s;
    SA[s*LDP + j] = (tg < LH) ? xbc[((size_t)b*LH + tg)*CONVD + hd*PDIM + j] : 0.f;
  }
  __syncthreads();
  // ---- Y1 = M X
  float4 y1[4];
#pragma unroll
  for (int j = 0; j < 4; ++j) y1[j] = make_float4(0.f,0.f,0.f,0.f);
  const float4* SC4 = (const float4*)SC;
#pragma unroll 2
  for (int s4 = 0; s4 < 16; ++s4) {
    float4 mj[4], xk[4];
#pragma unroll
    for (int j = 0; j < 4; ++j) mj[j] = SC4[(tr + 16*j)*(LDP/4) + s4];
#pragma unroll
    for (int k = 0; k < 4; ++k) xk[k] = SA4[(s4*4 + k)*(LDP/4) + tc];
#pragma unroll
    for (int j = 0; j < 4; ++j) {
      y1[j].x += mj[j].x*xk[0].x + mj[j].y*xk[1].x + mj[j].z*xk[2].x + mj[j].w*xk[3].x;
      y1[j].y += mj[j].x*xk[0].y + mj[j].y*xk[1].y + mj[j].z*xk[2].y + mj[j].w*xk[3].y;
      y1[j].z += mj[j].x*xk[0].z + mj[j].y*xk[1].z + mj[j].z*xk[2].z + mj[j].w*xk[3].z;
      y1[j].w += mj[j].x*xk[0].w + mj[j].y*xk[1].w + mj[j].z*xk[2].w + mj[j].w*xk[3].w;
    }
  }
  __syncthreads();
  size_t hbase = (size_t)blk*4096;
  for (int i = tid; i < 4096; i += 256) SC[(i >> 6)*LDP + (i & 63)] = Hin[hbase + i];
  __syncthreads();
  // ---- Y2 = C H_in^T
  float4 y2[4];
#pragma unroll
  for (int j = 0; j < 4; ++j) y2[j] = make_float4(0.f,0.f,0.f,0.f);
#pragma unroll 2
  for (int n4 = 0; n4 < 16; ++n4) {
    float4 cj[4], hk[4];
#pragma unroll
    for (int j = 0; j < 4; ++j) cj[j] = SB4[(tr + 16*j)*(LDP/4) + n4];
#pragma unroll
    for (int k = 0; k < 4; ++k) hk[k] = SC4[(n4*4 + k)*(LDP/4) + tc];
#pragma unroll
    for (int j = 0; j < 4; ++j) {
      y2[j].x += cj[j].x*hk[0].x + cj[j].y*hk[1].x + cj[j].z*hk[2].x + cj[j].w*hk[3].x;
      y2[j].y += cj[j].x*hk[0].y + cj[j].y*hk[1].y + cj[j].z*hk[2].y + cj[j].w*hk[3].y;
      y2[j].z += cj[j].x*hk[0].z + cj[j].y*hk[1].z + cj[j].z*hk[2].z + cj[j].w*hk[3].z;
      y2[j].w += cj[j].x*hk[0].w + cj[j].y*hk[1].w + cj[j].z*hk[2].w + cj[j].w*hk[3].w;
    }
  }
#pragma unroll
  for (int j = 0; j < 4; ++j) {
    int t = tr + 16*j, tg = t0 + t;
    if (tg < LH) {
      float pr = pref[t];
      float4 o;
      o.x = y1[j].x + pr*y2[j].x;
      o.y = y1[j].y + pr*y2[j].y;
      o.z = y1[j].z + pr*y2[j].z;
      o.w = y1[j].w + pr*y2[j].w;
      *(float4*)(y + ((size_t)b*LH + tg)*DIN + hd*PDIM + tc*4) = o;
    }
  }
}

// ---------------------------------------------------------------- gate + rmsnorm + out_proj
// Writes h (fp32) + hi/lo bf16 — casts fused.
#define TR5 8
__global__ void __launch_bounds__(256) k_out(
    const float* __restrict__ y, const float* __restrict__ xbc,
    const float* __restrict__ zx, const float* __restrict__ Dh,
    const float* __restrict__ nw, const float* __restrict__ owT,
    float* __restrict__ h, unsigned short* __restrict__ hH,
    unsigned short* __restrict__ hL) {
  const int nblk_l = 256;
  int b = blockIdx.x / nblk_l;
  int l0 = (blockIdx.x % nblk_l) * TR5;
  int t = threadIdx.x;
  __shared__ __align__(16) float yv[TR5][DIN];
  __shared__ float part[4][TR5][DIM];
  __shared__ float red[TR5][4];
  __shared__ float rs[TR5];
  int c = t;
  int hd = c >> 6;
  float dcoef = Dh[hd];
  float nwc = nw[c];
  float v[TR5];
#pragma unroll
  for (int r = 0; r < TR5; ++r) {
    int l = l0 + r;
    float val = 0.f;
    if (l < LH) {
      size_t row = (size_t)b*LH + l;
      float ys = y[row*DIN + c];
      float xh = xbc[row*CONVD + c];
      float z  = zx[row*DPROJ + c];
      val = (ys + dcoef*xh) * siluf_(z);
    }
    v[r] = val;
  }
  int wave = t >> 6, lane = t & 63;
#pragma unroll
  for (int r = 0; r < TR5; ++r) {
    float sq = v[r]*v[r];
    for (int off = 32; off > 0; off >>= 1) sq += __shfl_down(sq, off);
    if (lane == 0) red[r][wave] = sq;
  }
  __syncthreads();
  if (t < TR5) {
    float sm = red[t][0]+red[t][1]+red[t][2]+red[t][3];
    rs[t] = rsqrtf(sm/(float)DIN + 1e-5f);
  }
  __syncthreads();
#pragma unroll
  for (int r = 0; r < TR5; ++r) yv[r][c] = v[r] * rs[r] * nwc;
  __syncthreads();
  int jp = t & 63, q = t >> 6;
  int j0 = jp*2;
  float acc[2][TR5];
#pragma unroll
  for (int jj = 0; jj < 2; ++jj)
#pragma unroll
    for (int r = 0; r < TR5; ++r) acc[jj][r] = 0.f;
  const float* wtb = owT + (size_t)q*64*DIM + j0;
#pragma unroll 2
  for (int k4 = 0; k4 < 16; ++k4) {
    float2 w0 = *(const float2*)(wtb + (k4*4+0)*DIM);
    float2 w1 = *(const float2*)(wtb + (k4*4+1)*DIM);
    float2 w2_ = *(const float2*)(wtb + (k4*4+2)*DIM);
    float2 w3 = *(const float2*)(wtb + (k4*4+3)*DIM);
#pragma unroll
    for (int r = 0; r < TR5; ++r) {
      float4 hv = ((const float4*)&yv[r][q*64])[k4];
      acc[0][r] += w0.x*hv.x + w1.x*hv.y + w2_.x*hv.z + w3.x*hv.w;
      acc[1][r] += w0.y*hv.x + w1.y*hv.y + w2_.y*hv.z + w3.y*hv.w;
    }
  }
#pragma unroll
  for (int r = 0; r < TR5; ++r) {
    part[q][r][j0]   = acc[0][r];
    part[q][r][j0+1] = acc[1][r];
  }
  __syncthreads();
  if (t < DIM) {
#pragma unroll 2
    for (int r = 0; r < TR5; ++r) {
      int l = l0 + r;
      if (l < LH) {
        float val = part[0][r][t] + part[1][r][t] + part[2][r][t] + part[3][r][t];
        h[((size_t)b*LH + l)*DIM + t] = val;
        unsigned short hi = f2bf(val);
        hH[((size_t)b*LHP + l)*DIM + t] = hi;
        hL[((size_t)b*LHP + l)*DIM + t] = f2bf(val - bf2f(hi));
      }
    }
  }
}

// ---------------------------------------------------------------- final LN + head
__global__ void k_head(const float* __restrict__ h, const float* __restrict__ lnw,
                       const float* __restrict__ lnb, const float* __restrict__ hw,
                       const float* __restrict__ hb, float* __restrict__ out) {
  int b = blockIdx.x; int t = threadIdx.x;
  __shared__ float red[2];
  int wave = t >> 6, lane = t & 63;
  float v = h[((size_t)b*LH + LSEQ)*DIM + t];
  float s = v;
  for (int off = 32; off > 0; off >>= 1) s += __shfl_down(s, off);
  if (lane == 0) red[wave] = s;
  __syncthreads();
  float mean = (red[0]+red[1]) / (float)DIM;
  __syncthreads();
  float d = v - mean; float sq = d*d;
  for (int off = 32; off > 0; off >>= 1) sq += __shfl_down(sq, off);
  if (lane == 0) red[wave] = sq;
  __syncthreads();
  float var = (red[0]+red[1]) / (float)DIM;
  float cn = d*rsqrtf(var + 1e-5f)*lnw[t] + lnb[t];
  float dot = cn*hw[t];
  __syncthreads();
  for (int off = 32; off > 0; off >>= 1) dot += __shfl_down(dot, off);
  if (lane == 0) red[wave] = dot;
  __syncthreads();
  if (t == 0) out[b] = red[0]+red[1] + hb[0];
}

// ---------------------------------------------------------------- h -> d_out copy
__global__ void k_copy(const float* __restrict__ src, float* __restrict__ dst, long n4) {
  long i = (long)blockIdx.x*blockDim.x + threadIdx.x;
  if (i < n4) ((float4*)dst)[i] = ((const float4*)src)[i];
}

extern "C" void kernel_launch(void* const* d_in, const int* in_sizes, int n_in,
                              void* d_out, int out_size, void* d_ws, size_t ws_size,
                              hipStream_t stream) {
  const float* x     = (const float*)d_in[0];
  const float* w1    = (const float*)d_in[1];
  const float* b1    = (const float*)d_in[2];
  const float* w2    = (const float*)d_in[3];
  const float* b2    = (const float*)d_in[4];
  const float* cls   = (const float*)d_in[5];
  const float* inw   = (const float*)d_in[6];   // (4, 644, 128)
  const float* cw    = (const float*)d_in[7];   // (4, 384, 4)
  const float* cb    = (const float*)d_in[8];   // (4, 384)
  const float* dtb   = (const float*)d_in[9];   // (4, 4)
  const float* Alog  = (const float*)d_in[10];  // (4, 4)
  const float* Dh    = (const float*)d_in[11];  // (4, 4)
  const float* nw    = (const float*)d_in[12];  // (4, 256)
  const float* ow    = (const float*)d_in[13];  // (4, 128, 256)
  const float* lnw   = (const float*)d_in[14];
  const float* lnb   = (const float*)d_in[15];
  const float* hw    = (const float*)d_in[16];
  const float* hb    = (const float*)d_in[17];

  float* ws   = (float*)d_ws;
  float* hbuf = ws;                                   // 2,094,080
  float* zx   = hbuf + (size_t)BATCH*LH*DIM;          // 10,535,840
  float* xbc  = zx   + (size_t)BATCH*LH*DPROJ;        // 6,282,240
  float* ybuf = xbc  + (size_t)BATCH*LH*CONVD;        // 4,194,304 (G aliases ybuf)
  float* G    = ybuf;
  float* Hin  = ybuf + 4194304;                       // 4,194,304
  float* dec  = Hin  + 4194304;                       // 1,024
  float* owT  = dec  + 1024;                          // 131,072
  unsigned short* hH = (unsigned short*)(owT + 131072);    // 8*2048*128 u16
  unsigned short* hL = hH + (size_t)BATCH*LHP*DIM;         // 8*2048*128 u16
  unsigned short* wH = hL + (size_t)BATCH*LHP*DIM;         // 4*41*4*64*8 u16
  unsigned short* wL = wH + (size_t)DEPTH*NJT*4*64*8;      // same
  // total ~29.87M floats = 119.5 MiB

  k_cast_w<<<(DEPTH*NJT*4*64 + 255)/256, 256, 0, stream>>>(inw, wH, wL);
  k_transpose<<<dim3(4,2,4), 256, 0, stream>>>(ow, owT, DIM, DIN);

  k_front<<<BATCH*64 + 1, 256, 0, stream>>>(x, w1, b1, w2, b2, cls, hbuf, hH, hL);

  for (int i = 0; i < DEPTH; ++i) {
    k_inproj_mfma<<<BATCH*64, 256, 0, stream>>>(
        hH, hL, wH + (size_t)i*NJT*4*64*8, wL + (size_t)i*NJT*4*64*8,
        dtb + i*NH, zx);
    {
      long total = (long)BATCH*LH*(CONVD/4);
      k_conv<<<(int)((total + 255)/256), 256, 0, stream>>>(
          zx, cw + (size_t)i*CONVD*4, cb + (size_t)i*CONVD, xbc);
    }
    k_chunk_state<<<BATCH*NH*NCH, 256, 0, stream>>>(zx, xbc, Alog + i*NH, G, dec);
    k_combine<<<BATCH*NH*4, 256, 0, stream>>>(G, dec, Hin);
    k_chunk_out<<<BATCH*NH*NCH, 256, 0, stream>>>(zx, xbc, Alog + i*NH, Hin, ybuf);
    k_out<<<BATCH*256, 256, 0, stream>>>(
        ybuf, xbc, zx, Dh + i*NH, nw + (size_t)i*DIN, owT + (size_t)i*DIM*DIN,
        hbuf, hH, hL);
  }

  k_head<<<BATCH, 128, 0, stream>>>(hbuf, lnw, lnb, hw, hb, (float*)d_out);
  {
    long n4 = (long)BATCH*LH*DIM/4;
    k_copy<<<(int)((n4 + 255)/256), 256, 0, stream>>>(hbuf, (float*)d_out + 8, n4);
  }
}

// Round 15
// 689.473 us; speedup vs baseline: 1.2368x; 1.0848x over previous
//
#include <hip/hip_runtime.h>
#include <math.h>

// Shapes (fixed by setup_inputs)
#define BATCH 8
#define TSEQ 2048
#define CIN 3
#define WIN 5
#define LSEQ 2044          // T - WIN + 1
#define LH 2045            // LSEQ + 1 (cls token appended)
#define LHP 2048           // padded token rows for bf16 h buffers
#define DIM 128
#define DEPTH 4
#define DIN 256            // d_inner
#define NH 4               // heads
#define PDIM 64            // headdim
#define NSTATE 64          // d_state
#define CONVD 384          // d_inner + 2*d_state
#define DPROJ 644          // 2*d_inner + 2*d_state + nheads
#define NJT 41             // j-tiles of 16 (41*16 = 656 >= 644)
#define QC 64              // chunk length
#define NCH 32             // number of chunks
#define LDP 68             // padded LDS row stride (floats)
#define LDS2 68            // padded LDS row stride (shorts, bf16 frag buffers)
#define FTR 32             // tokens per k_front block

typedef __attribute__((ext_vector_type(8))) short bf16x8;
typedef __attribute__((ext_vector_type(4))) float f32x4;
union Frag8 { bf16x8 v; uint2 u[2]; };

__device__ __forceinline__ float sigmoidf_(float x){ return 1.f/(1.f+__expf(-x)); }
__device__ __forceinline__ float siluf_(float x){ return x*sigmoidf_(x); }
__device__ __forceinline__ unsigned short f2bf(float f){   // RNE fp32->bf16
  unsigned int u = __float_as_uint(f);
  return (unsigned short)((u + 0x7FFFu + ((u >> 16) & 1u)) >> 16);
}
__device__ __forceinline__ float bf2f(unsigned short u){
  return __uint_as_float(((unsigned int)u) << 16);
}
__device__ __forceinline__ unsigned int pack2(float a, float b){  // [lo addr]=a
  return (unsigned int)f2bf(a) | ((unsigned int)f2bf(b) << 16);
}
__device__ __forceinline__ unsigned int pack2lo(float a, float b){
  float ra = a - bf2f(f2bf(a)), rb = b - bf2f(f2bf(b));
  return (unsigned int)f2bf(ra) | ((unsigned int)f2bf(rb) << 16);
}
__device__ __forceinline__ bf16x8 ldfrag(const unsigned short* base, int off){
  Frag8 f;
  f.u[0] = *(const uint2*)(base + off);
  f.u[1] = *(const uint2*)(base + off + 4);
  return f.v;
}

// ---------------------------------------------------------------- weight transpose (ow only)
__global__ void __launch_bounds__(256) k_transpose(
    const float* __restrict__ src, float* __restrict__ dst, int R, int C) {
  __shared__ float tile[64][65];
  const float* s = src + (size_t)blockIdx.z*R*C;
  float* d = dst + (size_t)blockIdx.z*R*C;
  int r0 = blockIdx.y*64, c0 = blockIdx.x*64;
  int tx = threadIdx.x & 63, ty = threadIdx.x >> 6;
  for (int rr = ty; rr < 64; rr += 4) {
    int r = r0 + rr, c = c0 + tx;
    if (r < R && c < C) tile[rr][tx] = s[(size_t)r*C + c];
  }
  __syncthreads();
  for (int cc = ty; cc < 64; cc += 4) {
    int c = c0 + cc, r = r0 + tx;
    if (c < C && r < R) d[(size_t)c*R + r] = tile[tx][cc];
  }
}

// inw -> MFMA-fragment-order bf16 hi/lo: wS[layer][jt][kb][lane][8].
__global__ void __launch_bounds__(256) k_cast_w(
    const float* __restrict__ w, unsigned short* __restrict__ wH,
    unsigned short* __restrict__ wL) {
  int gid = blockIdx.x*256 + threadIdx.x;     // [ly][jt][kb][lane]
  if (gid >= DEPTH*NJT*4*64) return;
  int lane = gid & 63;
  int kb = (gid >> 6) & 3;
  int jt = (gid >> 8) % NJT;
  int ly = gid / (NJT*4*64);
  int m = lane & 15, q = lane >> 4;
  int j = jt*16 + m;
  int k = kb*32 + q*8;
  unsigned short hi[8], lo[8];
  if (j < DPROJ) {
    const float* src = w + ((size_t)ly*DPROJ + j)*DIM + k;
#pragma unroll
    for (int i = 0; i < 8; ++i) {
      float v = src[i];
      hi[i] = f2bf(v);
      lo[i] = f2bf(v - bf2f(hi[i]));
    }
  } else {
#pragma unroll
    for (int i = 0; i < 8; ++i) { hi[i] = 0; lo[i] = 0; }
  }
  size_t dst = (size_t)gid*8;
  *(uint4*)(wH + dst) = *(const uint4*)hi;
  *(uint4*)(wL + dst) = *(const uint4*)lo;
}

// ---------------------------------------------------------------- front MLP (writes h + hi/lo)
__global__ void __launch_bounds__(256) k_front(
    const float* __restrict__ x, const float* __restrict__ w1,
    const float* __restrict__ b1, const float* __restrict__ w2,
    const float* __restrict__ b2, const float* __restrict__ cls,
    float* __restrict__ h, unsigned short* __restrict__ hH,
    unsigned short* __restrict__ hL) {
  int t = threadIdx.x;
  if (blockIdx.x == BATCH*64) {              // cls rows
    if (t < DIM) {
      float cv = cls[t];
      unsigned short hi = f2bf(cv);
      unsigned short lo = f2bf(cv - bf2f(hi));
      for (int b = 0; b < BATCH; ++b) {
        h[((size_t)b*LH + LSEQ)*DIM + t] = cv;
        hH[((size_t)b*LHP + LSEQ)*DIM + t] = hi;
        hL[((size_t)b*LHP + LSEQ)*DIM + t] = lo;
      }
    }
    return;
  }
  int b = blockIdx.x >> 6;
  int c0 = (blockIdx.x & 63) * FTR;
  __shared__ float xs[(FTR+4)*CIN];
  __shared__ float w1s[DIM*17];
  __shared__ __align__(16) float h1s[FTR][DIM];
  __shared__ float part[FTR][DIM][2];
  for (int i = t; i < (FTR+4)*CIN; i += 256) {
    int row = c0 + i/3, ch = i - (i/3)*3;
    xs[i] = (row < TSEQ) ? x[(size_t)b*TSEQ*CIN + (size_t)row*CIN + ch] : 0.f;
  }
  for (int i = t; i < DIM*15; i += 256) {
    int j = i/15, k = i - j*15;
    w1s[j*17+k] = w1[i];
  }
  __syncthreads();
  {
    int j = t & 127, rh = t >> 7;
    float bias = b1[j];
    const float* wr = &w1s[j*17];
    for (int r = rh*16; r < rh*16+16; ++r) {
      float a = bias;
#pragma unroll
      for (int k = 0; k < 15; ++k) a += xs[r*3+k]*wr[k];
      h1s[r][j] = 0.5f*a*(1.f + erff(a*0.70710678118654752f));  // exact gelu
    }
  }
  __syncthreads();
  {
    int j = t & 127, hf = t >> 7;
    float4 wv[16];
    const float4* w2r = (const float4*)(w2 + (size_t)j*DIM + hf*64);
#pragma unroll
    for (int k4 = 0; k4 < 16; ++k4) wv[k4] = w2r[k4];
#pragma unroll 2
    for (int r = 0; r < FTR; ++r) {
      const float4* hr = (const float4*)&h1s[r][hf*64];
      float acc = 0.f;
#pragma unroll
      for (int k4 = 0; k4 < 16; ++k4) {
        float4 hv = hr[k4];
        acc += wv[k4].x*hv.x + wv[k4].y*hv.y + wv[k4].z*hv.z + wv[k4].w*hv.w;
      }
      part[r][j][hf] = acc;
    }
  }
  __syncthreads();
  if (t < DIM) {
    float bias = b2[t];
    for (int r = 0; r < FTR; ++r) {
      int l = c0 + r;
      if (l < LSEQ) {
        float val = part[r][t][0] + part[r][t][1] + bias;
        h[((size_t)b*LH + l)*DIM + t] = val;
        unsigned short hi = f2bf(val);
        hH[((size_t)b*LHP + l)*DIM + t] = hi;
        hL[((size_t)b*LHP + l)*DIM + t] = f2bf(val - bf2f(hi));
      }
    }
  }
}

// ---------------------------------------------------------------- in_proj via bf16x3 MFMA
__global__ void __launch_bounds__(256) k_inproj_mfma(
    const unsigned short* __restrict__ hH, const unsigned short* __restrict__ hL,
    const unsigned short* __restrict__ wH, const unsigned short* __restrict__ wL,
    const float* __restrict__ dtb, float* __restrict__ zx) {
  int b = blockIdx.x >> 6;
  int r = blockIdx.x & 63;
  int lb = r >> 1, jh = r & 1;
  int wv = threadIdx.x >> 6, lane = threadIdx.x & 63;
  int l0 = lb*64 + wv*16;
  int m = lane & 15, q = lane >> 4;
  size_t hoff = ((size_t)b*LHP + (l0 + m))*DIM + q*8;
  bf16x8 ah[4], al[4];
#pragma unroll
  for (int kb = 0; kb < 4; ++kb) {
    ah[kb] = *(const bf16x8*)(hH + hoff + kb*32);
    al[kb] = *(const bf16x8*)(hL + hoff + kb*32);
  }
  int jt0 = jh ? 21 : 0, jtn = jh ? NJT : 21;
#pragma unroll 2
  for (int jt = jt0; jt < jtn; ++jt) {
    size_t woff = (((size_t)jt*4)*64 + lane)*8;
    bf16x8 bh[4], bl[4];
#pragma unroll
    for (int kb = 0; kb < 4; ++kb) {
      bh[kb] = *(const bf16x8*)(wH + woff + (size_t)kb*64*8);  // coalesced
      bl[kb] = *(const bf16x8*)(wL + woff + (size_t)kb*64*8);
    }
    f32x4 acc = {0.f, 0.f, 0.f, 0.f};
#pragma unroll
    for (int kb = 0; kb < 4; ++kb)
      acc = __builtin_amdgcn_mfma_f32_16x16x32_bf16(al[kb], bh[kb], acc, 0, 0, 0);
#pragma unroll
    for (int kb = 0; kb < 4; ++kb)
      acc = __builtin_amdgcn_mfma_f32_16x16x32_bf16(ah[kb], bl[kb], acc, 0, 0, 0);
#pragma unroll
    for (int kb = 0; kb < 4; ++kb)
      acc = __builtin_amdgcn_mfma_f32_16x16x32_bf16(ah[kb], bh[kb], acc, 0, 0, 0);
    int jj = jt*16 + m;                     // D col = lane&15
    if (jj < DPROJ) {
      bool isdt = (jj >= 640);
      float bias = isdt ? dtb[jj - 640] : 0.f;
#pragma unroll
      for (int rr = 0; rr < 4; ++rr) {
        int tok = l0 + q*4 + rr;            // D row = q*4 + reg
        if (tok < LH) {
          float v = acc[rr];
          if (isdt) { v += bias; v = (v > 20.f) ? v : log1pf(__expf(v)); }
          zx[((size_t)b*LH + tok)*DPROJ + jj] = v;
        }
      }
    }
  }
}

// ---------------------------------------------------------------- causal dwconv + silu
__global__ void k_conv(const float* __restrict__ zx, const float* __restrict__ cw,
                       const float* __restrict__ cb, float* __restrict__ xbc) {
  size_t idx = (size_t)blockIdx.x*blockDim.x + threadIdx.x;
  const size_t total = (size_t)BATCH*LH*(CONVD/4);
  if (idx >= total) return;
  int c4 = (int)(idx % (CONVD/4)) * 4;
  size_t bl = idx / (CONVD/4);
  int l = (int)(bl % LH); int b = (int)(bl / LH);
  float4 w0 = *(const float4*)(cw + (c4+0)*4);
  float4 w1 = *(const float4*)(cw + (c4+1)*4);
  float4 w2 = *(const float4*)(cw + (c4+2)*4);
  float4 w3 = *(const float4*)(cw + (c4+3)*4);
  float4 a = *(const float4*)(cb + c4);
#pragma unroll
  for (int k = 0; k < 4; ++k) {
    int tin = l - 3 + k;
    if (tin >= 0) {
      float4 v = *(const float4*)(zx + ((size_t)b*LH + tin)*DPROJ + DIN + c4);
      a.x += v.x * ((const float*)&w0)[k];
      a.y += v.y * ((const float*)&w1)[k];
      a.z += v.z * ((const float*)&w2)[k];
      a.w += v.w * ((const float*)&w3)[k];
    }
  }
  float4 o;
  o.x = siluf_(a.x); o.y = siluf_(a.y); o.z = siluf_(a.z); o.w = siluf_(a.w);
  *(float4*)(xbc + ((size_t)b*LH + l)*CONVD + c4) = o;
}

// ---------------------------------------------------------------- chunked SSD, phase A
__global__ void __launch_bounds__(256) k_chunk_state(
    const float* __restrict__ zx, const float* __restrict__ xbc,
    const float* __restrict__ A_log, float* __restrict__ G, float* __restrict__ dec) {
  int blk = blockIdx.x;
  int c = blk & (NCH-1), hd = (blk >> 5) & 3, b = blk >> 7;
  int t0 = c*QC;
  int tid = threadIdx.x;
  float A = -__expf(A_log[hd]);
  __shared__ float xs[QC*PDIM];
  __shared__ float Bs[QC*NSTATE];
  __shared__ float coef[QC];
  if (tid < 64) {
    int tg = t0 + tid;
    float dtv = (tg < LH) ? zx[((size_t)b*LH + tg)*DPROJ + 640 + hd] : 0.f;
    float s = dtv;
#pragma unroll
    for (int off = 1; off < 64; off <<= 1) {
      float u = __shfl_up(s, off);
      if (tid >= off) s += u;
    }
    float cq = __shfl(s, 63);
    coef[tid] = __expf(A*(cq - s)) * dtv;
    if (tid == 63) dec[blk] = __expf(A * s);
  }
  for (int i = tid; i < QC*64; i += 256) {
    int s = i >> 6, j = i & 63;
    int tg = t0 + s;
    float xv = 0.f, bv = 0.f;
    if (tg < LH) {
      size_t row = ((size_t)b*LH + tg)*CONVD;
      xv = xbc[row + hd*PDIM + j];
      bv = xbc[row + DIN + j];
    }
    xs[i] = xv; Bs[i] = bv;
  }
  __syncthreads();
  int n = tid >> 2, q = tid & 3;
  float4 acc[4];
#pragma unroll
  for (int i4 = 0; i4 < 4; ++i4) acc[i4] = make_float4(0.f,0.f,0.f,0.f);
  const float4* xs4 = (const float4*)xs;
#pragma unroll 4
  for (int s = 0; s < QC; ++s) {            // capped unroll: keep VGPRs < spill
    float cb_ = coef[s] * Bs[s*64 + n];
#pragma unroll
    for (int i4 = 0; i4 < 4; ++i4) {
      float4 xv = xs4[s*16 + q*4 + i4];
      acc[i4].x += cb_*xv.x; acc[i4].y += cb_*xv.y;
      acc[i4].z += cb_*xv.z; acc[i4].w += cb_*xv.w;
    }
  }
  float4* gp = (float4*)(G + (size_t)blk*4096 + n*64 + q*16);
#pragma unroll
  for (int i4 = 0; i4 < 4; ++i4) gp[i4] = acc[i4];
}

// ---------------------------------------------------------------- phase B: inter-chunk
__global__ void __launch_bounds__(256) k_combine(
    const float* __restrict__ G, const float* __restrict__ dec, float* __restrict__ Hin) {
  int bh = blockIdx.x >> 2, esp = blockIdx.x & 3;
  int e = esp*1024 + threadIdx.x*4;
  size_t base0 = (size_t)bh*NCH*4096 + e;
  float4 H = make_float4(0.f,0.f,0.f,0.f);
  float4 g = *(const float4*)(G + base0);
  float d = dec[bh*NCH];
  for (int c = 0; c < NCH; ++c) {
    float4 gn = make_float4(0.f,0.f,0.f,0.f); float dn = 0.f;
    if (c + 1 < NCH) {
      gn = *(const float4*)(G + base0 + (size_t)(c+1)*4096);
      dn = dec[bh*NCH + c + 1];
    }
    *(float4*)(Hin + base0 + (size_t)c*4096) = H;   // carry-in for chunk c
    H.x = H.x*d + g.x; H.y = H.y*d + g.y; H.z = H.z*d + g.z; H.w = H.w*d + g.w;
    g = gn; d = dn;
  }
}

// ---------------------------------------------------------------- phase C: chunk output
// All three 64^3 matmuls on bf16x3 MFMA (fp32-equivalent); fp32 mask/scalars.
// S = C.B^T, Y2 = C.HT^T (shared A-frags), M = mask(S), Y1 = M.X^T-staged.
// grid 1024, block 256 (4 waves; wave w = output row-tile).
__global__ void __launch_bounds__(256) k_chunk_out(
    const float* __restrict__ zx, const float* __restrict__ xbc,
    const float* __restrict__ A_log, const float* __restrict__ Hin,
    float* __restrict__ y) {
  int blk = blockIdx.x;
  int c = blk & (NCH-1), hd = (blk >> 5) & 3, b = blk >> 7;
  int t0 = c*QC;
  int tid = threadIdx.x;
  int wv = tid >> 6, lane = tid & 63;
  int m = lane & 15, q = lane >> 4;
  float A = -__expf(A_log[hd]);
  __shared__ __align__(16) unsigned short CH[QC*LDS2], CL[QC*LDS2]; // C [t][n]
  __shared__ __align__(16) unsigned short BH[QC*LDS2], BL[QC*LDS2]; // B [s][n] -> M [t][s]
  __shared__ __align__(16) unsigned short TH[QC*LDS2], TL[QC*LDS2]; // HT [p][n] -> Xt [p][s]
  __shared__ float cum[QC], dts[QC], pref[QC];
  if (tid < 64) {
    int tg = t0 + tid;
    float dtv = (tg < LH) ? zx[((size_t)b*LH + tg)*DPROJ + 640 + hd] : 0.f;
    float s = dtv;
#pragma unroll
    for (int off = 1; off < 64; off <<= 1) {
      float u = __shfl_up(s, off);
      if (tid >= off) s += u;
    }
    dts[tid] = dtv; cum[tid] = s; pref[tid] = __expf(A*s);
  }
  // stage B and C (hi/lo, packed u32 writes of column pairs)
  for (int i = tid; i < 2048; i += 256) {
    int s = i >> 5, j2 = (i & 31)*2;
    int tg = t0 + s;
    float b0 = 0.f, b1 = 0.f, c0_ = 0.f, c1_ = 0.f;
    if (tg < LH) {
      size_t row = ((size_t)b*LH + tg)*CONVD;
      float2 bv = *(const float2*)(xbc + row + DIN + j2);
      float2 cv = *(const float2*)(xbc + row + DIN + NSTATE + j2);
      b0 = bv.x; b1 = bv.y; c0_ = cv.x; c1_ = cv.y;
    }
    int o = s*LDS2 + j2;
    *(unsigned int*)(BH + o) = pack2(b0, b1);
    *(unsigned int*)(BL + o) = pack2lo(b0, b1);
    *(unsigned int*)(CH + o) = pack2(c0_, c1_);
    *(unsigned int*)(CL + o) = pack2lo(c0_, c1_);
  }
  // stage HT transposed: TH[p][n] from Hin flat [n*64+p]
  size_t hbase = (size_t)blk*4096;
  for (int i = tid; i < 2048; i += 256) {
    int p = i & 63, n2 = (i >> 6)*2;
    float v0 = Hin[hbase + (size_t)n2*64 + p];
    float v1 = Hin[hbase + (size_t)(n2+1)*64 + p];
    int o = p*LDS2 + n2;
    *(unsigned int*)(TH + o) = pack2(v0, v1);
    *(unsigned int*)(TL + o) = pack2lo(v0, v1);
  }
  __syncthreads();
  // A-frags: C row-tile wv (shared by S and Y2)
  bf16x8 ch[2], cl[2];
#pragma unroll
  for (int kc = 0; kc < 2; ++kc) {
    int off = (wv*16 + m)*LDS2 + kc*32 + q*8;
    ch[kc] = ldfrag(CH, off);
    cl[kc] = ldfrag(CL, off);
  }
  // S = C.B^T and Y2 = C.HT^T
  f32x4 sacc[4], y2a[4];
#pragma unroll
  for (int nt = 0; nt < 4; ++nt) {
    f32x4 a1 = {0.f,0.f,0.f,0.f}, a2 = {0.f,0.f,0.f,0.f};
#pragma unroll
    for (int kc = 0; kc < 2; ++kc) {
      int off = (nt*16 + m)*LDS2 + kc*32 + q*8;
      bf16x8 bh = ldfrag(BH, off), bl = ldfrag(BL, off);
      bf16x8 th = ldfrag(TH, off), tl = ldfrag(TL, off);
      a1 = __builtin_amdgcn_mfma_f32_16x16x32_bf16(cl[kc], bh, a1, 0, 0, 0);
      a1 = __builtin_amdgcn_mfma_f32_16x16x32_bf16(ch[kc], bl, a1, 0, 0, 0);
      a1 = __builtin_amdgcn_mfma_f32_16x16x32_bf16(ch[kc], bh, a1, 0, 0, 0);
      a2 = __builtin_amdgcn_mfma_f32_16x16x32_bf16(cl[kc], th, a2, 0, 0, 0);
      a2 = __builtin_amdgcn_mfma_f32_16x16x32_bf16(ch[kc], tl, a2, 0, 0, 0);
      a2 = __builtin_amdgcn_mfma_f32_16x16x32_bf16(ch[kc], th, a2, 0, 0, 0);
    }
    sacc[nt] = a1; y2a[nt] = a2;
  }
  __syncthreads();   // all waves done reading BH/TH before overwrite
  // mask S -> M (fp32), write hi/lo into BH/BL as [t][s]
#pragma unroll
  for (int nt = 0; nt < 4; ++nt) {
    int s = nt*16 + m;
#pragma unroll
    for (int r = 0; r < 4; ++r) {
      int t = wv*16 + q*4 + r;
      float mv = 0.f;
      if (s <= t) mv = sacc[nt][r] * __expf(A*(cum[t] - cum[s])) * dts[s];
      unsigned short hi = f2bf(mv);
      BH[t*LDS2 + s] = hi;
      BL[t*LDS2 + s] = f2bf(mv - bf2f(hi));
    }
  }
  // stage Xt [p][s] into TH/TL (overwrite HT)
  for (int i = tid; i < 2048; i += 256) {
    int p = i & 63, s2 = (i >> 6)*2;
    int tg = t0 + s2;
    float v0 = (tg < LH)   ? xbc[((size_t)b*LH + tg)*CONVD + hd*PDIM + p]   : 0.f;
    float v1 = (tg+1 < LH) ? xbc[((size_t)b*LH + tg+1)*CONVD + hd*PDIM + p] : 0.f;
    int o = p*LDS2 + s2;
    *(unsigned int*)(TH + o) = pack2(v0, v1);
    *(unsigned int*)(TL + o) = pack2lo(v0, v1);
  }
  __syncthreads();
  // Y1 = M.Xt^T : A = M row-tile wv, B = Xt
  bf16x8 mh[2], ml[2];
#pragma unroll
  for (int kc = 0; kc < 2; ++kc) {
    int off = (wv*16 + m)*LDS2 + kc*32 + q*8;
    mh[kc] = ldfrag(BH, off);
    ml[kc] = ldfrag(BL, off);
  }
#pragma unroll
  for (int nt = 0; nt < 4; ++nt) {
    f32x4 a1 = {0.f,0.f,0.f,0.f};
#pragma unroll
    for (int kc = 0; kc < 2; ++kc) {
      int off = (nt*16 + m)*LDS2 + kc*32 + q*8;
      bf16x8 th = ldfrag(TH, off), tl = ldfrag(TL, off);
      a1 = __builtin_amdgcn_mfma_f32_16x16x32_bf16(ml[kc], th, a1, 0, 0, 0);
      a1 = __builtin_amdgcn_mfma_f32_16x16x32_bf16(mh[kc], tl, a1, 0, 0, 0);
      a1 = __builtin_amdgcn_mfma_f32_16x16x32_bf16(mh[kc], th, a1, 0, 0, 0);
    }
    // combine + store: D row = t, col = p
    int p = nt*16 + m;
#pragma unroll
    for (int r = 0; r < 4; ++r) {
      int t = wv*16 + q*4 + r, tg = t0 + t;
      if (tg < LH)
        y[((size_t)b*LH + tg)*DIN + hd*PDIM + p] = a1[r] + pref[t]*y2a[nt][r];
    }
  }
}

// ---------------------------------------------------------------- gate + rmsnorm + out_proj
#define TR5 8
__global__ void __launch_bounds__(256) k_out(
    const float* __restrict__ y, const float* __restrict__ xbc,
    const float* __restrict__ zx, const float* __restrict__ Dh,
    const float* __restrict__ nw, const float* __restrict__ owT,
    float* __restrict__ h, unsigned short* __restrict__ hH,
    unsigned short* __restrict__ hL) {
  const int nblk_l = 256;
  int b = blockIdx.x / nblk_l;
  int l0 = (blockIdx.x % nblk_l) * TR5;
  int t = threadIdx.x;
  __shared__ __align__(16) float yv[TR5][DIN];
  __shared__ float part[4][TR5][DIM];
  __shared__ float red[TR5][4];
  __shared__ float rs[TR5];
  int c = t;
  int hd = c >> 6;
  float dcoef = Dh[hd];
  float nwc = nw[c];
  float v[TR5];
#pragma unroll
  for (int r = 0; r < TR5; ++r) {
    int l = l0 + r;
    float val = 0.f;
    if (l < LH) {
      size_t row = (size_t)b*LH + l;
      float ys = y[row*DIN + c];
      float xh = xbc[row*CONVD + c];
      float z  = zx[row*DPROJ + c];
      val = (ys + dcoef*xh) * siluf_(z);
    }
    v[r] = val;
  }
  int wave = t >> 6, lane = t & 63;
#pragma unroll
  for (int r = 0; r < TR5; ++r) {
    float sq = v[r]*v[r];
    for (int off = 32; off > 0; off >>= 1) sq += __shfl_down(sq, off);
    if (lane == 0) red[r][wave] = sq;
  }
  __syncthreads();
  if (t < TR5) {
    float sm = red[t][0]+red[t][1]+red[t][2]+red[t][3];
    rs[t] = rsqrtf(sm/(float)DIN + 1e-5f);
  }
  __syncthreads();
#pragma unroll
  for (int r = 0; r < TR5; ++r) yv[r][c] = v[r] * rs[r] * nwc;
  __syncthreads();
  int jp = t & 63, q = t >> 6;
  int j0 = jp*2;
  float acc[2][TR5];
#pragma unroll
  for (int jj = 0; jj < 2; ++jj)
#pragma unroll
    for (int r = 0; r < TR5; ++r) acc[jj][r] = 0.f;
  const float* wtb = owT + (size_t)q*64*DIM + j0;
#pragma unroll 2
  for (int k4 = 0; k4 < 16; ++k4) {
    float2 w0 = *(const float2*)(wtb + (k4*4+0)*DIM);
    float2 w1 = *(const float2*)(wtb + (k4*4+1)*DIM);
    float2 w2_ = *(const float2*)(wtb + (k4*4+2)*DIM);
    float2 w3 = *(const float2*)(wtb + (k4*4+3)*DIM);
#pragma unroll
    for (int r = 0; r < TR5; ++r) {
      float4 hv = ((const float4*)&yv[r][q*64])[k4];
      acc[0][r] += w0.x*hv.x + w1.x*hv.y + w2_.x*hv.z + w3.x*hv.w;
      acc[1][r] += w0.y*hv.x + w1.y*hv.y + w2_.y*hv.z + w3.y*hv.w;
    }
  }
#pragma unroll
  for (int r = 0; r < TR5; ++r) {
    part[q][r][j0]   = acc[0][r];
    part[q][r][j0+1] = acc[1][r];
  }
  __syncthreads();
  if (t < DIM) {
#pragma unroll 2
    for (int r = 0; r < TR5; ++r) {
      int l = l0 + r;
      if (l < LH) {
        float val = part[0][r][t] + part[1][r][t] + part[2][r][t] + part[3][r][t];
        h[((size_t)b*LH + l)*DIM + t] = val;
        unsigned short hi = f2bf(val);
        hH[((size_t)b*LHP + l)*DIM + t] = hi;
        hL[((size_t)b*LHP + l)*DIM + t] = f2bf(val - bf2f(hi));
      }
    }
  }
}

// ---------------------------------------------------------------- final LN + head
__global__ void k_head(const float* __restrict__ h, const float* __restrict__ lnw,
                       const float* __restrict__ lnb, const float* __restrict__ hw,
                       const float* __restrict__ hb, float* __restrict__ out) {
  int b = blockIdx.x; int t = threadIdx.x;
  __shared__ float red[2];
  int wave = t >> 6, lane = t & 63;
  float v = h[((size_t)b*LH + LSEQ)*DIM + t];
  float s = v;
  for (int off = 32; off > 0; off >>= 1) s += __shfl_down(s, off);
  if (lane == 0) red[wave] = s;
  __syncthreads();
  float mean = (red[0]+red[1]) / (float)DIM;
  __syncthreads();
  float d = v - mean; float sq = d*d;
  for (int off = 32; off > 0; off >>= 1) sq += __shfl_down(sq, off);
  if (lane == 0) red[wave] = sq;
  __syncthreads();
  float var = (red[0]+red[1]) / (float)DIM;
  float cn = d*rsqrtf(var + 1e-5f)*lnw[t] + lnb[t];
  float dot = cn*hw[t];
  __syncthreads();
  for (int off = 32; off > 0; off >>= 1) dot += __shfl_down(dot, off);
  if (lane == 0) red[wave] = dot;
  __syncthreads();
  if (t == 0) out[b] = red[0]+red[1] + hb[0];
}

// ---------------------------------------------------------------- h -> d_out copy
__global__ void k_copy(const float* __restrict__ src, float* __restrict__ dst, long n4) {
  long i = (long)blockIdx.x*blockDim.x + threadIdx.x;
  if (i < n4) ((float4*)dst)[i] = ((const float4*)src)[i];
}

extern "C" void kernel_launch(void* const* d_in, const int* in_sizes, int n_in,
                              void* d_out, int out_size, void* d_ws, size_t ws_size,
                              hipStream_t stream) {
  const float* x     = (const float*)d_in[0];
  const float* w1    = (const float*)d_in[1];
  const float* b1    = (const float*)d_in[2];
  const float* w2    = (const float*)d_in[3];
  const float* b2    = (const float*)d_in[4];
  const float* cls   = (const float*)d_in[5];
  const float* inw   = (const float*)d_in[6];   // (4, 644, 128)
  const float* cw    = (const float*)d_in[7];   // (4, 384, 4)
  const float* cb    = (const float*)d_in[8];   // (4, 384)
  const float* dtb   = (const float*)d_in[9];   // (4, 4)
  const float* Alog  = (const float*)d_in[10];  // (4, 4)
  const float* Dh    = (const float*)d_in[11];  // (4, 4)
  const float* nw    = (const float*)d_in[12];  // (4, 256)
  const float* ow    = (const float*)d_in[13];  // (4, 128, 256)
  const float* lnw   = (const float*)d_in[14];
  const float* lnb   = (const float*)d_in[15];
  const float* hw    = (const float*)d_in[16];
  const float* hb    = (const float*)d_in[17];

  float* ws   = (float*)d_ws;
  float* hbuf = ws;                                   // 2,094,080
  float* zx   = hbuf + (size_t)BATCH*LH*DIM;          // 10,535,840
  float* xbc  = zx   + (size_t)BATCH*LH*DPROJ;        // 6,282,240
  float* ybuf = xbc  + (size_t)BATCH*LH*CONVD;        // 4,194,304 (G aliases ybuf)
  float* G    = ybuf;
  float* Hin  = ybuf + 4194304;                       // 4,194,304
  float* dec  = Hin  + 4194304;                       // 1,024
  float* owT  = dec  + 1024;                          // 131,072
  unsigned short* hH = (unsigned short*)(owT + 131072);    // 8*2048*128 u16
  unsigned short* hL = hH + (size_t)BATCH*LHP*DIM;         // 8*2048*128 u16
  unsigned short* wH = hL + (size_t)BATCH*LHP*DIM;         // 4*41*4*64*8 u16
  unsigned short* wL = wH + (size_t)DEPTH*NJT*4*64*8;      // same
  // total ~29.87M floats = 119.5 MiB

  k_cast_w<<<(DEPTH*NJT*4*64 + 255)/256, 256, 0, stream>>>(inw, wH, wL);
  k_transpose<<<dim3(4,2,4), 256, 0, stream>>>(ow, owT, DIM, DIN);

  k_front<<<BATCH*64 + 1, 256, 0, stream>>>(x, w1, b1, w2, b2, cls, hbuf, hH, hL);

  for (int i = 0; i < DEPTH; ++i) {
    k_inproj_mfma<<<BATCH*64, 256, 0, stream>>>(
        hH, hL, wH + (size_t)i*NJT*4*64*8, wL + (size_t)i*NJT*4*64*8,
        dtb + i*NH, zx);
    {
      long total = (long)BATCH*LH*(CONVD/4);
      k_conv<<<(int)((total + 255)/256), 256, 0, stream>>>(
          zx, cw + (size_t)i*CONVD*4, cb + (size_t)i*CONVD, xbc);
    }
    k_chunk_state<<<BATCH*NH*NCH, 256, 0, stream>>>(zx, xbc, Alog + i*NH, G, dec);
    k_combine<<<BATCH*NH*4, 256, 0, stream>>>(G, dec, Hin);
    k_chunk_out<<<BATCH*NH*NCH, 256, 0, stream>>>(zx, xbc, Alog + i*NH, Hin, ybuf);
    k_out<<<BATCH*256, 256, 0, stream>>>(
        ybuf, xbc, zx, Dh + i*NH, nw + (size_t)i*DIN, owT + (size_t)i*DIM*DIN,
        hbuf, hH, hL);
  }

  k_head<<<BATCH, 128, 0, stream>>>(hbuf, lnw, lnb, hw, hb, (float*)d_out);
  {
    long n4 = (long)BATCH*LH*DIM/4;
    k_copy<<<(int)((n4 + 255)/256), 256, 0, stream>>>(hbuf, (float*)d_out + 8, n4);
  }
}

// Round 16
// 611.041 us; speedup vs baseline: 1.3955x; 1.1284x over previous
//
#include <hip/hip_runtime.h>
#include <math.h>

// Shapes (fixed by setup_inputs)
#define BATCH 8
#define TSEQ 2048
#define CIN 3
#define WIN 5
#define LSEQ 2044          // T - WIN + 1
#define LH 2045            // LSEQ + 1 (cls token appended)
#define LHP 2048           // padded token rows for bf16 h buffers
#define DIM 128
#define DEPTH 4
#define DIN 256            // d_inner
#define NH 4               // heads
#define PDIM 64            // headdim
#define NSTATE 64          // d_state
#define CONVD 384          // d_inner + 2*d_state
#define DPROJ 644          // 2*d_inner + 2*d_state + nheads
#define NJT 41             // j-tiles of 16 (41*16 = 656 >= 644)
#define QC 64              // chunk length
#define NCH 32             // number of chunks
#define LDS2 68            // padded LDS row stride (shorts, 64-col frag buffers)
#define LDSY 264           // padded LDS row stride (shorts, 256-col k_out buffer)
#define FTR 32             // tokens per k_front block

typedef __attribute__((ext_vector_type(8))) short bf16x8;
typedef __attribute__((ext_vector_type(4))) float f32x4;
union Frag8 { bf16x8 v; uint2 u[2]; };

__device__ __forceinline__ float sigmoidf_(float x){ return 1.f/(1.f+__expf(-x)); }
__device__ __forceinline__ float siluf_(float x){ return x*sigmoidf_(x); }
__device__ __forceinline__ unsigned short f2bf(float f){   // RNE fp32->bf16
  unsigned int u = __float_as_uint(f);
  return (unsigned short)((u + 0x7FFFu + ((u >> 16) & 1u)) >> 16);
}
__device__ __forceinline__ float bf2f(unsigned short u){
  return __uint_as_float(((unsigned int)u) << 16);
}
__device__ __forceinline__ unsigned int pack2(float a, float b){  // [lo addr]=a
  return (unsigned int)f2bf(a) | ((unsigned int)f2bf(b) << 16);
}
__device__ __forceinline__ unsigned int pack2lo(float a, float b){
  float ra = a - bf2f(f2bf(a)), rb = b - bf2f(f2bf(b));
  return (unsigned int)f2bf(ra) | ((unsigned int)f2bf(rb) << 16);
}
__device__ __forceinline__ bf16x8 ldfrag(const unsigned short* base, int off){
  Frag8 f;
  f.u[0] = *(const uint2*)(base + off);
  f.u[1] = *(const uint2*)(base + off + 4);
  return f.v;
}

// inw -> MFMA-fragment-order bf16 hi/lo: wS[layer][jt][kb][lane][8].
__global__ void __launch_bounds__(256) k_cast_w(
    const float* __restrict__ w, unsigned short* __restrict__ wH,
    unsigned short* __restrict__ wL) {
  int gid = blockIdx.x*256 + threadIdx.x;     // [ly][jt][kb][lane]
  if (gid >= DEPTH*NJT*4*64) return;
  int lane = gid & 63;
  int kb = (gid >> 6) & 3;
  int jt = (gid >> 8) % NJT;
  int ly = gid / (NJT*4*64);
  int m = lane & 15, q = lane >> 4;
  int j = jt*16 + m;
  int k = kb*32 + q*8;
  unsigned short hi[8], lo[8];
  if (j < DPROJ) {
    const float* src = w + ((size_t)ly*DPROJ + j)*DIM + k;
#pragma unroll
    for (int i = 0; i < 8; ++i) {
      float v = src[i];
      hi[i] = f2bf(v);
      lo[i] = f2bf(v - bf2f(hi[i]));
    }
  } else {
#pragma unroll
    for (int i = 0; i < 8; ++i) { hi[i] = 0; lo[i] = 0; }
  }
  size_t dst = (size_t)gid*8;
  *(uint4*)(wH + dst) = *(const uint4*)hi;
  *(uint4*)(wL + dst) = *(const uint4*)lo;
}

// ow (4,128,256) -> fragment-order bf16 hi/lo: oS[layer][jt(8)][kb(8)][lane][8].
__global__ void __launch_bounds__(256) k_cast_ow(
    const float* __restrict__ ow, unsigned short* __restrict__ oH,
    unsigned short* __restrict__ oL) {
  int gid = blockIdx.x*256 + threadIdx.x;
  if (gid >= DEPTH*8*8*64) return;
  int lane = gid & 63;
  int kb = (gid >> 6) & 7;
  int jt = (gid >> 9) & 7;
  int ly = gid >> 12;
  int m = lane & 15, q = lane >> 4;
  int j = jt*16 + m;
  int k = kb*32 + q*8;
  const float* src = ow + ((size_t)ly*DIM + j)*DIN + k;
  unsigned short hi[8], lo[8];
#pragma unroll
  for (int i = 0; i < 8; ++i) {
    float v = src[i];
    hi[i] = f2bf(v);
    lo[i] = f2bf(v - bf2f(hi[i]));
  }
  size_t dst = (size_t)gid*8;
  *(uint4*)(oH + dst) = *(const uint4*)hi;
  *(uint4*)(oL + dst) = *(const uint4*)lo;
}

// ---------------------------------------------------------------- front MLP (writes h + hi/lo)
__global__ void __launch_bounds__(256) k_front(
    const float* __restrict__ x, const float* __restrict__ w1,
    const float* __restrict__ b1, const float* __restrict__ w2,
    const float* __restrict__ b2, const float* __restrict__ cls,
    float* __restrict__ h, unsigned short* __restrict__ hH,
    unsigned short* __restrict__ hL) {
  int t = threadIdx.x;
  if (blockIdx.x == BATCH*64) {              // cls rows
    if (t < DIM) {
      float cv = cls[t];
      unsigned short hi = f2bf(cv);
      unsigned short lo = f2bf(cv - bf2f(hi));
      for (int b = 0; b < BATCH; ++b) {
        h[((size_t)b*LH + LSEQ)*DIM + t] = cv;
        hH[((size_t)b*LHP + LSEQ)*DIM + t] = hi;
        hL[((size_t)b*LHP + LSEQ)*DIM + t] = lo;
      }
    }
    return;
  }
  int b = blockIdx.x >> 6;
  int c0 = (blockIdx.x & 63) * FTR;
  __shared__ float xs[(FTR+4)*CIN];
  __shared__ float w1s[DIM*17];
  __shared__ __align__(16) float h1s[FTR][DIM];
  __shared__ float part[FTR][DIM][2];
  for (int i = t; i < (FTR+4)*CIN; i += 256) {
    int row = c0 + i/3, ch = i - (i/3)*3;
    xs[i] = (row < TSEQ) ? x[(size_t)b*TSEQ*CIN + (size_t)row*CIN + ch] : 0.f;
  }
  for (int i = t; i < DIM*15; i += 256) {
    int j = i/15, k = i - j*15;
    w1s[j*17+k] = w1[i];
  }
  __syncthreads();
  {
    int j = t & 127, rh = t >> 7;
    float bias = b1[j];
    const float* wr = &w1s[j*17];
    for (int r = rh*16; r < rh*16+16; ++r) {
      float a = bias;
#pragma unroll
      for (int k = 0; k < 15; ++k) a += xs[r*3+k]*wr[k];
      h1s[r][j] = 0.5f*a*(1.f + erff(a*0.70710678118654752f));  // exact gelu
    }
  }
  __syncthreads();
  {
    int j = t & 127, hf = t >> 7;
    float4 wv[16];
    const float4* w2r = (const float4*)(w2 + (size_t)j*DIM + hf*64);
#pragma unroll
    for (int k4 = 0; k4 < 16; ++k4) wv[k4] = w2r[k4];
#pragma unroll 2
    for (int r = 0; r < FTR; ++r) {
      const float4* hr = (const float4*)&h1s[r][hf*64];
      float acc = 0.f;
#pragma unroll
      for (int k4 = 0; k4 < 16; ++k4) {
        float4 hv = hr[k4];
        acc += wv[k4].x*hv.x + wv[k4].y*hv.y + wv[k4].z*hv.z + wv[k4].w*hv.w;
      }
      part[r][j][hf] = acc;
    }
  }
  __syncthreads();
  if (t < DIM) {
    float bias = b2[t];
    for (int r = 0; r < FTR; ++r) {
      int l = c0 + r;
      if (l < LSEQ) {
        float val = part[r][t][0] + part[r][t][1] + bias;
        h[((size_t)b*LH + l)*DIM + t] = val;
        unsigned short hi = f2bf(val);
        hH[((size_t)b*LHP + l)*DIM + t] = hi;
        hL[((size_t)b*LHP + l)*DIM + t] = f2bf(val - bf2f(hi));
      }
    }
  }
}

// ---------------------------------------------------------------- in_proj via bf16x3 MFMA
__global__ void __launch_bounds__(256) k_inproj_mfma(
    const unsigned short* __restrict__ hH, const unsigned short* __restrict__ hL,
    const unsigned short* __restrict__ wH, const unsigned short* __restrict__ wL,
    const float* __restrict__ dtb, float* __restrict__ zx) {
  int b = blockIdx.x >> 6;
  int r = blockIdx.x & 63;
  int lb = r >> 1, jh = r & 1;
  int wv = threadIdx.x >> 6, lane = threadIdx.x & 63;
  int l0 = lb*64 + wv*16;
  int m = lane & 15, q = lane >> 4;
  size_t hoff = ((size_t)b*LHP + (l0 + m))*DIM + q*8;
  bf16x8 ah[4], al[4];
#pragma unroll
  for (int kb = 0; kb < 4; ++kb) {
    ah[kb] = *(const bf16x8*)(hH + hoff + kb*32);
    al[kb] = *(const bf16x8*)(hL + hoff + kb*32);
  }
  int jt0 = jh ? 21 : 0, jtn = jh ? NJT : 21;
#pragma unroll 2
  for (int jt = jt0; jt < jtn; ++jt) {
    size_t woff = (((size_t)jt*4)*64 + lane)*8;
    bf16x8 bh[4], bl[4];
#pragma unroll
    for (int kb = 0; kb < 4; ++kb) {
      bh[kb] = *(const bf16x8*)(wH + woff + (size_t)kb*64*8);  // coalesced
      bl[kb] = *(const bf16x8*)(wL + woff + (size_t)kb*64*8);
    }
    f32x4 acc = {0.f, 0.f, 0.f, 0.f};
#pragma unroll
    for (int kb = 0; kb < 4; ++kb)
      acc = __builtin_amdgcn_mfma_f32_16x16x32_bf16(al[kb], bh[kb], acc, 0, 0, 0);
#pragma unroll
    for (int kb = 0; kb < 4; ++kb)
      acc = __builtin_amdgcn_mfma_f32_16x16x32_bf16(ah[kb], bl[kb], acc, 0, 0, 0);
#pragma unroll
    for (int kb = 0; kb < 4; ++kb)
      acc = __builtin_amdgcn_mfma_f32_16x16x32_bf16(ah[kb], bh[kb], acc, 0, 0, 0);
    int jj = jt*16 + m;                     // D col = lane&15
    if (jj < DPROJ) {
      bool isdt = (jj >= 640);
      float bias = isdt ? dtb[jj - 640] : 0.f;
#pragma unroll
      for (int rr = 0; rr < 4; ++rr) {
        int tok = l0 + q*4 + rr;            // D row = q*4 + reg
        if (tok < LH) {
          float v = acc[rr];
          if (isdt) { v += bias; v = (v > 20.f) ? v : log1pf(__expf(v)); }
          zx[((size_t)b*LH + tok)*DPROJ + jj] = v;
        }
      }
    }
  }
}

// ---------------------------------------------------------------- causal dwconv + silu
__global__ void k_conv(const float* __restrict__ zx, const float* __restrict__ cw,
                       const float* __restrict__ cb, float* __restrict__ xbc) {
  size_t idx = (size_t)blockIdx.x*blockDim.x + threadIdx.x;
  const size_t total = (size_t)BATCH*LH*(CONVD/4);
  if (idx >= total) return;
  int c4 = (int)(idx % (CONVD/4)) * 4;
  size_t bl = idx / (CONVD/4);
  int l = (int)(bl % LH); int b = (int)(bl / LH);
  float4 w0 = *(const float4*)(cw + (c4+0)*4);
  float4 w1 = *(const float4*)(cw + (c4+1)*4);
  float4 w2 = *(const float4*)(cw + (c4+2)*4);
  float4 w3 = *(const float4*)(cw + (c4+3)*4);
  float4 a = *(const float4*)(cb + c4);
#pragma unroll
  for (int k = 0; k < 4; ++k) {
    int tin = l - 3 + k;
    if (tin >= 0) {
      float4 v = *(const float4*)(zx + ((size_t)b*LH + tin)*DPROJ + DIN + c4);
      a.x += v.x * ((const float*)&w0)[k];
      a.y += v.y * ((const float*)&w1)[k];
      a.z += v.z * ((const float*)&w2)[k];
      a.w += v.w * ((const float*)&w3)[k];
    }
  }
  float4 o;
  o.x = siluf_(a.x); o.y = siluf_(a.y); o.z = siluf_(a.z); o.w = siluf_(a.w);
  *(float4*)(xbc + ((size_t)b*LH + l)*CONVD + c4) = o;
}

// ---------------------------------------------------------------- chunked SSD, phase A
// G[n][p] = sum_s (coef_s*B_s[n]) * X_s[p]  via bf16x3 MFMA (fp32-equivalent).
// A = Bc[n][s], B-op = Xt[p][s]; D row = n (q*4+reg + wv*16), col = p (nt*16+m).
__global__ void __launch_bounds__(256) k_chunk_state(
    const float* __restrict__ zx, const float* __restrict__ xbc,
    const float* __restrict__ A_log, float* __restrict__ G, float* __restrict__ dec) {
  int blk = blockIdx.x;
  int c = blk & (NCH-1), hd = (blk >> 5) & 3, b = blk >> 7;
  int t0 = c*QC;
  int tid = threadIdx.x;
  int wv = tid >> 6, lane = tid & 63;
  int m = lane & 15, q = lane >> 4;
  float A = -__expf(A_log[hd]);
  __shared__ __align__(16) unsigned short BcH[QC*LDS2], BcL[QC*LDS2]; // [n][s]
  __shared__ __align__(16) unsigned short XtH[QC*LDS2], XtL[QC*LDS2]; // [p][s]
  __shared__ float coef[QC];
  if (tid < 64) {
    int tg = t0 + tid;
    float dtv = (tg < LH) ? zx[((size_t)b*LH + tg)*DPROJ + 640 + hd] : 0.f;
    float s = dtv;
#pragma unroll
    for (int off = 1; off < 64; off <<= 1) {
      float u = __shfl_up(s, off);
      if (tid >= off) s += u;
    }
    float cq = __shfl(s, 63);
    coef[tid] = __expf(A*(cq - s)) * dtv;
    if (tid == 63) dec[blk] = __expf(A * s);
  }
  __syncthreads();
  for (int i = tid; i < 2048; i += 256) {
    int n = i & 63, s2 = (i >> 6)*2;
    int tg0 = t0 + s2, tg1 = t0 + s2 + 1;
    float b0 = 0.f, b1 = 0.f, x0 = 0.f, x1 = 0.f;
    if (tg0 < LH) {
      size_t row = ((size_t)b*LH + tg0)*CONVD;
      b0 = xbc[row + DIN + n] * coef[s2];
      x0 = xbc[row + hd*PDIM + n];
    }
    if (tg1 < LH) {
      size_t row = ((size_t)b*LH + tg1)*CONVD;
      b1 = xbc[row + DIN + n] * coef[s2+1];
      x1 = xbc[row + hd*PDIM + n];
    }
    int o = n*LDS2 + s2;
    *(unsigned int*)(BcH + o) = pack2(b0, b1);
    *(unsigned int*)(BcL + o) = pack2lo(b0, b1);
    *(unsigned int*)(XtH + o) = pack2(x0, x1);
    *(unsigned int*)(XtL + o) = pack2lo(x0, x1);
  }
  __syncthreads();
  bf16x8 ah[2], al[2];
#pragma unroll
  for (int kc = 0; kc < 2; ++kc) {
    int off = (wv*16 + m)*LDS2 + kc*32 + q*8;
    ah[kc] = ldfrag(BcH, off);
    al[kc] = ldfrag(BcL, off);
  }
#pragma unroll
  for (int nt = 0; nt < 4; ++nt) {
    f32x4 acc = {0.f,0.f,0.f,0.f};
#pragma unroll
    for (int kc = 0; kc < 2; ++kc) {
      int off = (nt*16 + m)*LDS2 + kc*32 + q*8;
      bf16x8 xh = ldfrag(XtH, off), xl = ldfrag(XtL, off);
      acc = __builtin_amdgcn_mfma_f32_16x16x32_bf16(al[kc], xh, acc, 0, 0, 0);
      acc = __builtin_amdgcn_mfma_f32_16x16x32_bf16(ah[kc], xl, acc, 0, 0, 0);
      acc = __builtin_amdgcn_mfma_f32_16x16x32_bf16(ah[kc], xh, acc, 0, 0, 0);
    }
    int p = nt*16 + m;
#pragma unroll
    for (int r = 0; r < 4; ++r) {
      int n = wv*16 + q*4 + r;
      G[(size_t)blk*4096 + n*64 + p] = acc[r];
    }
  }
}

// ---------------------------------------------------------------- phase B: inter-chunk
__global__ void __launch_bounds__(256) k_combine(
    const float* __restrict__ G, const float* __restrict__ dec, float* __restrict__ Hin) {
  int bh = blockIdx.x >> 2, esp = blockIdx.x & 3;
  int e = esp*1024 + threadIdx.x*4;
  size_t base0 = (size_t)bh*NCH*4096 + e;
  float4 H = make_float4(0.f,0.f,0.f,0.f);
  float4 g = *(const float4*)(G + base0);
  float d = dec[bh*NCH];
  for (int c = 0; c < NCH; ++c) {
    float4 gn = make_float4(0.f,0.f,0.f,0.f); float dn = 0.f;
    if (c + 1 < NCH) {
      gn = *(const float4*)(G + base0 + (size_t)(c+1)*4096);
      dn = dec[bh*NCH + c + 1];
    }
    *(float4*)(Hin + base0 + (size_t)c*4096) = H;   // carry-in for chunk c
    H.x = H.x*d + g.x; H.y = H.y*d + g.y; H.z = H.z*d + g.z; H.w = H.w*d + g.w;
    g = gn; d = dn;
  }
}

// ---------------------------------------------------------------- phase C: chunk output
// All three 64^3 matmuls on bf16x3 MFMA; fp32 mask/scalars. (R15-verified.)
__global__ void __launch_bounds__(256) k_chunk_out(
    const float* __restrict__ zx, const float* __restrict__ xbc,
    const float* __restrict__ A_log, const float* __restrict__ Hin,
    float* __restrict__ y) {
  int blk = blockIdx.x;
  int c = blk & (NCH-1), hd = (blk >> 5) & 3, b = blk >> 7;
  int t0 = c*QC;
  int tid = threadIdx.x;
  int wv = tid >> 6, lane = tid & 63;
  int m = lane & 15, q = lane >> 4;
  float A = -__expf(A_log[hd]);
  __shared__ __align__(16) unsigned short CH[QC*LDS2], CL[QC*LDS2]; // C [t][n]
  __shared__ __align__(16) unsigned short BH[QC*LDS2], BL[QC*LDS2]; // B [s][n] -> M [t][s]
  __shared__ __align__(16) unsigned short TH[QC*LDS2], TL[QC*LDS2]; // HT [p][n] -> Xt [p][s]
  __shared__ float cum[QC], dts[QC], pref[QC];
  if (tid < 64) {
    int tg = t0 + tid;
    float dtv = (tg < LH) ? zx[((size_t)b*LH + tg)*DPROJ + 640 + hd] : 0.f;
    float s = dtv;
#pragma unroll
    for (int off = 1; off < 64; off <<= 1) {
      float u = __shfl_up(s, off);
      if (tid >= off) s += u;
    }
    dts[tid] = dtv; cum[tid] = s; pref[tid] = __expf(A*s);
  }
  for (int i = tid; i < 2048; i += 256) {
    int s = i >> 5, j2 = (i & 31)*2;
    int tg = t0 + s;
    float b0 = 0.f, b1 = 0.f, c0_ = 0.f, c1_ = 0.f;
    if (tg < LH) {
      size_t row = ((size_t)b*LH + tg)*CONVD;
      float2 bv = *(const float2*)(xbc + row + DIN + j2);
      float2 cv = *(const float2*)(xbc + row + DIN + NSTATE + j2);
      b0 = bv.x; b1 = bv.y; c0_ = cv.x; c1_ = cv.y;
    }
    int o = s*LDS2 + j2;
    *(unsigned int*)(BH + o) = pack2(b0, b1);
    *(unsigned int*)(BL + o) = pack2lo(b0, b1);
    *(unsigned int*)(CH + o) = pack2(c0_, c1_);
    *(unsigned int*)(CL + o) = pack2lo(c0_, c1_);
  }
  size_t hbase = (size_t)blk*4096;
  for (int i = tid; i < 2048; i += 256) {
    int p = i & 63, n2 = (i >> 6)*2;
    float v0 = Hin[hbase + (size_t)n2*64 + p];
    float v1 = Hin[hbase + (size_t)(n2+1)*64 + p];
    int o = p*LDS2 + n2;
    *(unsigned int*)(TH + o) = pack2(v0, v1);
    *(unsigned int*)(TL + o) = pack2lo(v0, v1);
  }
  __syncthreads();
  bf16x8 ch[2], cl[2];
#pragma unroll
  for (int kc = 0; kc < 2; ++kc) {
    int off = (wv*16 + m)*LDS2 + kc*32 + q*8;
    ch[kc] = ldfrag(CH, off);
    cl[kc] = ldfrag(CL, off);
  }
  f32x4 sacc[4], y2a[4];
#pragma unroll
  for (int nt = 0; nt < 4; ++nt) {
    f32x4 a1 = {0.f,0.f,0.f,0.f}, a2 = {0.f,0.f,0.f,0.f};
#pragma unroll
    for (int kc = 0; kc < 2; ++kc) {
      int off = (nt*16 + m)*LDS2 + kc*32 + q*8;
      bf16x8 bh = ldfrag(BH, off), bl = ldfrag(BL, off);
      bf16x8 th = ldfrag(TH, off), tl = ldfrag(TL, off);
      a1 = __builtin_amdgcn_mfma_f32_16x16x32_bf16(cl[kc], bh, a1, 0, 0, 0);
      a1 = __builtin_amdgcn_mfma_f32_16x16x32_bf16(ch[kc], bl, a1, 0, 0, 0);
      a1 = __builtin_amdgcn_mfma_f32_16x16x32_bf16(ch[kc], bh, a1, 0, 0, 0);
      a2 = __builtin_amdgcn_mfma_f32_16x16x32_bf16(cl[kc], th, a2, 0, 0, 0);
      a2 = __builtin_amdgcn_mfma_f32_16x16x32_bf16(ch[kc], tl, a2, 0, 0, 0);
      a2 = __builtin_amdgcn_mfma_f32_16x16x32_bf16(ch[kc], th, a2, 0, 0, 0);
    }
    sacc[nt] = a1; y2a[nt] = a2;
  }
  __syncthreads();   // all waves done reading BH/TH before overwrite
#pragma unroll
  for (int nt = 0; nt < 4; ++nt) {
    int s = nt*16 + m;
#pragma unroll
    for (int r = 0; r < 4; ++r) {
      int t = wv*16 + q*4 + r;
      float mv = 0.f;
      if (s <= t) mv = sacc[nt][r] * __expf(A*(cum[t] - cum[s])) * dts[s];
      unsigned short hi = f2bf(mv);
      BH[t*LDS2 + s] = hi;
      BL[t*LDS2 + s] = f2bf(mv - bf2f(hi));
    }
  }
  for (int i = tid; i < 2048; i += 256) {
    int p = i & 63, s2 = (i >> 6)*2;
    int tg = t0 + s2;
    float v0 = (tg < LH)   ? xbc[((size_t)b*LH + tg)*CONVD + hd*PDIM + p]   : 0.f;
    float v1 = (tg+1 < LH) ? xbc[((size_t)b*LH + tg+1)*CONVD + hd*PDIM + p] : 0.f;
    int o = p*LDS2 + s2;
    *(unsigned int*)(TH + o) = pack2(v0, v1);
    *(unsigned int*)(TL + o) = pack2lo(v0, v1);
  }
  __syncthreads();
  bf16x8 mh[2], ml[2];
#pragma unroll
  for (int kc = 0; kc < 2; ++kc) {
    int off = (wv*16 + m)*LDS2 + kc*32 + q*8;
    mh[kc] = ldfrag(BH, off);
    ml[kc] = ldfrag(BL, off);
  }
#pragma unroll
  for (int nt = 0; nt < 4; ++nt) {
    f32x4 a1 = {0.f,0.f,0.f,0.f};
#pragma unroll
    for (int kc = 0; kc < 2; ++kc) {
      int off = (nt*16 + m)*LDS2 + kc*32 + q*8;
      bf16x8 th = ldfrag(TH, off), tl = ldfrag(TL, off);
      a1 = __builtin_amdgcn_mfma_f32_16x16x32_bf16(ml[kc], th, a1, 0, 0, 0);
      a1 = __builtin_amdgcn_mfma_f32_16x16x32_bf16(mh[kc], tl, a1, 0, 0, 0);
      a1 = __builtin_amdgcn_mfma_f32_16x16x32_bf16(mh[kc], th, a1, 0, 0, 0);
    }
    int p = nt*16 + m;
#pragma unroll
    for (int r = 0; r < 4; ++r) {
      int t = wv*16 + q*4 + r, tg = t0 + t;
      if (tg < LH)
        y[((size_t)b*LH + tg)*DIN + hd*PDIM + p] = a1[r] + pref[t]*y2a[nt][r];
    }
  }
}

// ---------------------------------------------------------------- gate + rmsnorm + out_proj
// 16 tokens/block; out_proj via bf16x3 MFMA with pre-swizzled ow fragments.
__global__ void __launch_bounds__(256) k_out(
    const float* __restrict__ y, const float* __restrict__ xbc,
    const float* __restrict__ zx, const float* __restrict__ Dh,
    const float* __restrict__ nw, const unsigned short* __restrict__ oH,
    const unsigned short* __restrict__ oL, float* __restrict__ h,
    unsigned short* __restrict__ hH, unsigned short* __restrict__ hL) {
  int b = blockIdx.x >> 7;
  int l0 = (blockIdx.x & 127) * 16;
  int t = threadIdx.x;
  __shared__ __align__(16) unsigned short yH[16*LDSY], yL[16*LDSY];
  __shared__ float red[16][4];
  __shared__ float rs[16];
  int c = t;
  int hd = c >> 6;
  float dcoef = Dh[hd];
  float nwc = nw[c];
  float v[16];
#pragma unroll
  for (int r = 0; r < 16; ++r) {
    int l = l0 + r;
    float val = 0.f;
    if (l < LH) {
      size_t row = (size_t)b*LH + l;
      float ys = y[row*DIN + c];
      float xh = xbc[row*CONVD + c];
      float z  = zx[row*DPROJ + c];
      val = (ys + dcoef*xh) * siluf_(z);
    }
    v[r] = val;
  }
  int wave = t >> 6, lane = t & 63;
#pragma unroll
  for (int r = 0; r < 16; ++r) {
    float sq = v[r]*v[r];
    for (int off = 32; off > 0; off >>= 1) sq += __shfl_down(sq, off);
    if (lane == 0) red[r][wave] = sq;
  }
  __syncthreads();
  if (t < 16) {
    float sm = red[t][0]+red[t][1]+red[t][2]+red[t][3];
    rs[t] = rsqrtf(sm/(float)DIN + 1e-5f);
  }
  __syncthreads();
#pragma unroll
  for (int r = 0; r < 16; ++r) {
    float val = v[r] * rs[r] * nwc;
    unsigned short hi = f2bf(val);
    yH[r*LDSY + c] = hi;
    yL[r*LDSY + c] = f2bf(val - bf2f(hi));
  }
  __syncthreads();
  int m = lane & 15, q = lane >> 4;
  bf16x8 ah[8], al[8];
#pragma unroll
  for (int kb = 0; kb < 8; ++kb) {
    int off = m*LDSY + kb*32 + q*8;
    ah[kb] = ldfrag(yH, off);
    al[kb] = ldfrag(yL, off);
  }
#pragma unroll
  for (int jtp = 0; jtp < 2; ++jtp) {
    int jt = wave*2 + jtp;
    f32x4 acc = {0.f,0.f,0.f,0.f};
#pragma unroll
    for (int kb = 0; kb < 8; ++kb) {
      size_t woff = (((size_t)jt*8 + kb)*64 + lane)*8;   // coalesced
      bf16x8 bh = *(const bf16x8*)(oH + woff);
      bf16x8 bl = *(const bf16x8*)(oL + woff);
      acc = __builtin_amdgcn_mfma_f32_16x16x32_bf16(al[kb], bh, acc, 0, 0, 0);
      acc = __builtin_amdgcn_mfma_f32_16x16x32_bf16(ah[kb], bl, acc, 0, 0, 0);
      acc = __builtin_amdgcn_mfma_f32_16x16x32_bf16(ah[kb], bh, acc, 0, 0, 0);
    }
    int j = jt*16 + m;                      // D col = lane&15
#pragma unroll
    for (int r = 0; r < 4; ++r) {
      int l = l0 + q*4 + r;                 // D row = q*4 + reg
      if (l < LH) {
        float val = acc[r];
        h[((size_t)b*LH + l)*DIM + j] = val;
        unsigned short hi = f2bf(val);
        hH[((size_t)b*LHP + l)*DIM + j] = hi;
        hL[((size_t)b*LHP + l)*DIM + j] = f2bf(val - bf2f(hi));
      }
    }
  }
}

// ---------------------------------------------------------------- final LN + head
__global__ void k_head(const float* __restrict__ h, const float* __restrict__ lnw,
                       const float* __restrict__ lnb, const float* __restrict__ hw,
                       const float* __restrict__ hb, float* __restrict__ out) {
  int b = blockIdx.x; int t = threadIdx.x;
  __shared__ float red[2];
  int wave = t >> 6, lane = t & 63;
  float v = h[((size_t)b*LH + LSEQ)*DIM + t];
  float s = v;
  for (int off = 32; off > 0; off >>= 1) s += __shfl_down(s, off);
  if (lane == 0) red[wave] = s;
  __syncthreads();
  float mean = (red[0]+red[1]) / (float)DIM;
  __syncthreads();
  float d = v - mean; float sq = d*d;
  for (int off = 32; off > 0; off >>= 1) sq += __shfl_down(sq, off);
  if (lane == 0) red[wave] = sq;
  __syncthreads();
  float var = (red[0]+red[1]) / (float)DIM;
  float cn = d*rsqrtf(var + 1e-5f)*lnw[t] + lnb[t];
  float dot = cn*hw[t];
  __syncthreads();
  for (int off = 32; off > 0; off >>= 1) dot += __shfl_down(dot, off);
  if (lane == 0) red[wave] = dot;
  __syncthreads();
  if (t == 0) out[b] = red[0]+red[1] + hb[0];
}

// ---------------------------------------------------------------- h -> d_out copy
__global__ void k_copy(const float* __restrict__ src, float* __restrict__ dst, long n4) {
  long i = (long)blockIdx.x*blockDim.x + threadIdx.x;
  if (i < n4) ((float4*)dst)[i] = ((const float4*)src)[i];
}

extern "C" void kernel_launch(void* const* d_in, const int* in_sizes, int n_in,
                              void* d_out, int out_size, void* d_ws, size_t ws_size,
                              hipStream_t stream) {
  const float* x     = (const float*)d_in[0];
  const float* w1    = (const float*)d_in[1];
  const float* b1    = (const float*)d_in[2];
  const float* w2    = (const float*)d_in[3];
  const float* b2    = (const float*)d_in[4];
  const float* cls   = (const float*)d_in[5];
  const float* inw   = (const float*)d_in[6];   // (4, 644, 128)
  const float* cw    = (const float*)d_in[7];   // (4, 384, 4)
  const float* cb    = (const float*)d_in[8];   // (4, 384)
  const float* dtb   = (const float*)d_in[9];   // (4, 4)
  const float* Alog  = (const float*)d_in[10];  // (4, 4)
  const float* Dh    = (const float*)d_in[11];  // (4, 4)
  const float* nw    = (const float*)d_in[12];  // (4, 256)
  const float* ow    = (const float*)d_in[13];  // (4, 128, 256)
  const float* lnw   = (const float*)d_in[14];
  const float* lnb   = (const float*)d_in[15];
  const float* hw    = (const float*)d_in[16];
  const float* hb    = (const float*)d_in[17];

  float* ws   = (float*)d_ws;
  float* hbuf = ws;                                   // 2,094,080
  float* zx   = hbuf + (size_t)BATCH*LH*DIM;          // 10,535,840
  float* xbc  = zx   + (size_t)BATCH*LH*DPROJ;        // 6,282,240
  float* ybuf = xbc  + (size_t)BATCH*LH*CONVD;        // 4,194,304 (G aliases ybuf)
  float* G    = ybuf;
  float* Hin  = ybuf + 4194304;                       // 4,194,304
  float* dec  = Hin  + 4194304;                       // 1,024
  unsigned short* hH = (unsigned short*)(dec + 1024);      // 8*2048*128 u16
  unsigned short* hL = hH + (size_t)BATCH*LHP*DIM;         // 8*2048*128 u16
  unsigned short* wH = hL + (size_t)BATCH*LHP*DIM;         // 4*41*4*64*8 u16
  unsigned short* wL = wH + (size_t)DEPTH*NJT*4*64*8;      // same
  unsigned short* oH = wL + (size_t)DEPTH*NJT*4*64*8;      // 4*8*8*64*8 u16
  unsigned short* oL = oH + (size_t)DEPTH*8*8*64*8;        // same
  // total ~29.9M floats = 119.6 MiB

  k_cast_w<<<(DEPTH*NJT*4*64 + 255)/256, 256, 0, stream>>>(inw, wH, wL);
  k_cast_ow<<<(DEPTH*8*8*64 + 255)/256, 256, 0, stream>>>(ow, oH, oL);

  k_front<<<BATCH*64 + 1, 256, 0, stream>>>(x, w1, b1, w2, b2, cls, hbuf, hH, hL);

  for (int i = 0; i < DEPTH; ++i) {
    k_inproj_mfma<<<BATCH*64, 256, 0, stream>>>(
        hH, hL, wH + (size_t)i*NJT*4*64*8, wL + (size_t)i*NJT*4*64*8,
        dtb + i*NH, zx);
    {
      long total = (long)BATCH*LH*(CONVD/4);
      k_conv<<<(int)((total + 255)/256), 256, 0, stream>>>(
          zx, cw + (size_t)i*CONVD*4, cb + (size_t)i*CONVD, xbc);
    }
    k_chunk_state<<<BATCH*NH*NCH, 256, 0, stream>>>(zx, xbc, Alog + i*NH, G, dec);
    k_combine<<<BATCH*NH*4, 256, 0, stream>>>(G, dec, Hin);
    k_chunk_out<<<BATCH*NH*NCH, 256, 0, stream>>>(zx, xbc, Alog + i*NH, Hin, ybuf);
    k_out<<<BATCH*128, 256, 0, stream>>>(
        ybuf, xbc, zx, Dh + i*NH, nw + (size_t)i*DIN,
        oH + (size_t)i*8*8*64*8, oL + (size_t)i*8*8*64*8, hbuf, hH, hL);
  }

  k_head<<<BATCH, 128, 0, stream>>>(hbuf, lnw, lnb, hw, hb, (float*)d_out);
  {
    long n4 = (long)BATCH*LH*DIM/4;
    k_copy<<<(int)((n4 + 255)/256), 256, 0, stream>>>(hbuf, (float*)d_out + 8, n4);
  }
}

// Round 17
// 566.780 us; speedup vs baseline: 1.5045x; 1.0781x over previous
//
#include <hip/hip_runtime.h>
#include <math.h>

// Shapes (fixed by setup_inputs)
#define BATCH 8
#define TSEQ 2048
#define CIN 3
#define WIN 5
#define LSEQ 2044          // T - WIN + 1
#define LH 2045            // LSEQ + 1 (cls token appended)
#define LHP 2048           // padded token rows for bf16 h buffers
#define DIM 128
#define DEPTH 4
#define DIN 256            // d_inner
#define NH 4               // heads
#define PDIM 64            // headdim
#define NSTATE 64          // d_state
#define CONVD 384          // d_inner + 2*d_state
#define DPROJ 644          // 2*d_inner + 2*d_state + nheads
#define NJT 41             // j-tiles of 16 (41*16 = 656 >= 644)
#define QC 64              // chunk length
#define NCH 32             // number of chunks
#define LDS2 68            // padded LDS row stride (shorts, 64-col frag buffers)
#define LDSY 264           // padded LDS row stride (shorts, 256-col k_out buffer)
#define LDSH 136           // padded LDS row stride (shorts, 128-col h tile)
#define FTR 32             // tokens per k_front block

typedef __attribute__((ext_vector_type(8))) short bf16x8;
typedef __attribute__((ext_vector_type(4))) float f32x4;
union Frag8 { bf16x8 v; uint2 u[2]; };

__device__ __forceinline__ float sigmoidf_(float x){ return 1.f/(1.f+__expf(-x)); }
__device__ __forceinline__ float siluf_(float x){ return x*sigmoidf_(x); }
__device__ __forceinline__ unsigned short f2bf(float f){   // RNE fp32->bf16
  unsigned int u = __float_as_uint(f);
  return (unsigned short)((u + 0x7FFFu + ((u >> 16) & 1u)) >> 16);
}
__device__ __forceinline__ float bf2f(unsigned short u){
  return __uint_as_float(((unsigned int)u) << 16);
}
__device__ __forceinline__ unsigned int pack2(float a, float b){  // [lo addr]=a
  return (unsigned int)f2bf(a) | ((unsigned int)f2bf(b) << 16);
}
__device__ __forceinline__ unsigned int pack2lo(float a, float b){
  float ra = a - bf2f(f2bf(a)), rb = b - bf2f(f2bf(b));
  return (unsigned int)f2bf(ra) | ((unsigned int)f2bf(rb) << 16);
}
__device__ __forceinline__ bf16x8 ldfrag(const unsigned short* base, int off){
  Frag8 f;
  f.u[0] = *(const uint2*)(base + off);
  f.u[1] = *(const uint2*)(base + off + 4);
  return f.v;
}

// inw -> MFMA-fragment-order bf16 hi/lo: wS[layer][jt][kb][lane][8].
__global__ void __launch_bounds__(256) k_cast_w(
    const float* __restrict__ w, unsigned short* __restrict__ wH,
    unsigned short* __restrict__ wL) {
  int gid = blockIdx.x*256 + threadIdx.x;     // [ly][jt][kb][lane]
  if (gid >= DEPTH*NJT*4*64) return;
  int lane = gid & 63;
  int kb = (gid >> 6) & 3;
  int jt = (gid >> 8) % NJT;
  int ly = gid / (NJT*4*64);
  int m = lane & 15, q = lane >> 4;
  int j = jt*16 + m;
  int k = kb*32 + q*8;
  unsigned short hi[8], lo[8];
  if (j < DPROJ) {
    const float* src = w + ((size_t)ly*DPROJ + j)*DIM + k;
#pragma unroll
    for (int i = 0; i < 8; ++i) {
      float v = src[i];
      hi[i] = f2bf(v);
      lo[i] = f2bf(v - bf2f(hi[i]));
    }
  } else {
#pragma unroll
    for (int i = 0; i < 8; ++i) { hi[i] = 0; lo[i] = 0; }
  }
  size_t dst = (size_t)gid*8;
  *(uint4*)(wH + dst) = *(const uint4*)hi;
  *(uint4*)(wL + dst) = *(const uint4*)lo;
}

// ow (4,128,256) -> fragment-order bf16 hi/lo: oS[layer][jt(8)][kb(8)][lane][8].
__global__ void __launch_bounds__(256) k_cast_ow(
    const float* __restrict__ ow, unsigned short* __restrict__ oH,
    unsigned short* __restrict__ oL) {
  int gid = blockIdx.x*256 + threadIdx.x;
  if (gid >= DEPTH*8*8*64) return;
  int lane = gid & 63;
  int kb = (gid >> 6) & 7;
  int jt = (gid >> 9) & 7;
  int ly = gid >> 12;
  int m = lane & 15, q = lane >> 4;
  int j = jt*16 + m;
  int k = kb*32 + q*8;
  const float* src = ow + ((size_t)ly*DIM + j)*DIN + k;
  unsigned short hi[8], lo[8];
#pragma unroll
  for (int i = 0; i < 8; ++i) {
    float v = src[i];
    hi[i] = f2bf(v);
    lo[i] = f2bf(v - bf2f(hi[i]));
  }
  size_t dst = (size_t)gid*8;
  *(uint4*)(oH + dst) = *(const uint4*)hi;
  *(uint4*)(oL + dst) = *(const uint4*)lo;
}

// ---------------------------------------------------------------- front MLP (writes hi/lo only)
__global__ void __launch_bounds__(256) k_front(
    const float* __restrict__ x, const float* __restrict__ w1,
    const float* __restrict__ b1, const float* __restrict__ w2,
    const float* __restrict__ b2, const float* __restrict__ cls,
    unsigned short* __restrict__ hH, unsigned short* __restrict__ hL) {
  int t = threadIdx.x;
  if (blockIdx.x == BATCH*64) {              // cls rows
    if (t < DIM) {
      float cv = cls[t];
      unsigned short hi = f2bf(cv);
      unsigned short lo = f2bf(cv - bf2f(hi));
      for (int b = 0; b < BATCH; ++b) {
        hH[((size_t)b*LHP + LSEQ)*DIM + t] = hi;
        hL[((size_t)b*LHP + LSEQ)*DIM + t] = lo;
      }
    }
    return;
  }
  int b = blockIdx.x >> 6;
  int c0 = (blockIdx.x & 63) * FTR;
  __shared__ float xs[(FTR+4)*CIN];
  __shared__ float w1s[DIM*17];
  __shared__ __align__(16) float h1s[FTR][DIM];
  __shared__ float part[FTR][DIM][2];
  for (int i = t; i < (FTR+4)*CIN; i += 256) {
    int row = c0 + i/3, ch = i - (i/3)*3;
    xs[i] = (row < TSEQ) ? x[(size_t)b*TSEQ*CIN + (size_t)row*CIN + ch] : 0.f;
  }
  for (int i = t; i < DIM*15; i += 256) {
    int j = i/15, k = i - j*15;
    w1s[j*17+k] = w1[i];
  }
  __syncthreads();
  {
    int j = t & 127, rh = t >> 7;
    float bias = b1[j];
    const float* wr = &w1s[j*17];
    for (int r = rh*16; r < rh*16+16; ++r) {
      float a = bias;
#pragma unroll
      for (int k = 0; k < 15; ++k) a += xs[r*3+k]*wr[k];
      h1s[r][j] = 0.5f*a*(1.f + erff(a*0.70710678118654752f));  // exact gelu
    }
  }
  __syncthreads();
  {
    int j = t & 127, hf = t >> 7;
    float4 wv[16];
    const float4* w2r = (const float4*)(w2 + (size_t)j*DIM + hf*64);
#pragma unroll
    for (int k4 = 0; k4 < 16; ++k4) wv[k4] = w2r[k4];
#pragma unroll 2
    for (int r = 0; r < FTR; ++r) {
      const float4* hr = (const float4*)&h1s[r][hf*64];
      float acc = 0.f;
#pragma unroll
      for (int k4 = 0; k4 < 16; ++k4) {
        float4 hv = hr[k4];
        acc += wv[k4].x*hv.x + wv[k4].y*hv.y + wv[k4].z*hv.z + wv[k4].w*hv.w;
      }
      part[r][j][hf] = acc;
    }
  }
  __syncthreads();
  if (t < DIM) {
    float bias = b2[t];
    for (int r = 0; r < FTR; ++r) {
      int l = c0 + r;
      if (l < LSEQ) {
        float val = part[r][t][0] + part[r][t][1] + bias;
        unsigned short hi = f2bf(val);
        hH[((size_t)b*LHP + l)*DIM + t] = hi;
        hL[((size_t)b*LHP + l)*DIM + t] = f2bf(val - bf2f(hi));
      }
    }
  }
}

// ---------------------------------------------------------------- in_proj via bf16x3 MFMA
// (layer 0 only — layers 1..3 are fused into k_out_fused)
__global__ void __launch_bounds__(256) k_inproj_mfma(
    const unsigned short* __restrict__ hH, const unsigned short* __restrict__ hL,
    const unsigned short* __restrict__ wH, const unsigned short* __restrict__ wL,
    const float* __restrict__ dtb, float* __restrict__ zx) {
  int b = blockIdx.x >> 6;
  int r = blockIdx.x & 63;
  int lb = r >> 1, jh = r & 1;
  int wv = threadIdx.x >> 6, lane = threadIdx.x & 63;
  int l0 = lb*64 + wv*16;
  int m = lane & 15, q = lane >> 4;
  size_t hoff = ((size_t)b*LHP + (l0 + m))*DIM + q*8;
  bf16x8 ah[4], al[4];
#pragma unroll
  for (int kb = 0; kb < 4; ++kb) {
    ah[kb] = *(const bf16x8*)(hH + hoff + kb*32);
    al[kb] = *(const bf16x8*)(hL + hoff + kb*32);
  }
  int jt0 = jh ? 21 : 0, jtn = jh ? NJT : 21;
#pragma unroll 2
  for (int jt = jt0; jt < jtn; ++jt) {
    size_t woff = (((size_t)jt*4)*64 + lane)*8;
    bf16x8 bh[4], bl[4];
#pragma unroll
    for (int kb = 0; kb < 4; ++kb) {
      bh[kb] = *(const bf16x8*)(wH + woff + (size_t)kb*64*8);  // coalesced
      bl[kb] = *(const bf16x8*)(wL + woff + (size_t)kb*64*8);
    }
    f32x4 acc = {0.f, 0.f, 0.f, 0.f};
#pragma unroll
    for (int kb = 0; kb < 4; ++kb)
      acc = __builtin_amdgcn_mfma_f32_16x16x32_bf16(al[kb], bh[kb], acc, 0, 0, 0);
#pragma unroll
    for (int kb = 0; kb < 4; ++kb)
      acc = __builtin_amdgcn_mfma_f32_16x16x32_bf16(ah[kb], bl[kb], acc, 0, 0, 0);
#pragma unroll
    for (int kb = 0; kb < 4; ++kb)
      acc = __builtin_amdgcn_mfma_f32_16x16x32_bf16(ah[kb], bh[kb], acc, 0, 0, 0);
    int jj = jt*16 + m;                     // D col = lane&15
    if (jj < DPROJ) {
      bool isdt = (jj >= 640);
      float bias = isdt ? dtb[jj - 640] : 0.f;
#pragma unroll
      for (int rr = 0; rr < 4; ++rr) {
        int tok = l0 + q*4 + rr;            // D row = q*4 + reg
        if (tok < LH) {
          float v = acc[rr];
          if (isdt) { v += bias; v = (v > 20.f) ? v : log1pf(__expf(v)); }
          zx[((size_t)b*LH + tok)*DPROJ + jj] = v;
        }
      }
    }
  }
}

// ---------------------------------------------------------------- causal dwconv + silu
__global__ void k_conv(const float* __restrict__ zx, const float* __restrict__ cw,
                       const float* __restrict__ cb, float* __restrict__ xbc) {
  size_t idx = (size_t)blockIdx.x*blockDim.x + threadIdx.x;
  const size_t total = (size_t)BATCH*LH*(CONVD/4);
  if (idx >= total) return;
  int c4 = (int)(idx % (CONVD/4)) * 4;
  size_t bl = idx / (CONVD/4);
  int l = (int)(bl % LH); int b = (int)(bl / LH);
  float4 w0 = *(const float4*)(cw + (c4+0)*4);
  float4 w1 = *(const float4*)(cw + (c4+1)*4);
  float4 w2 = *(const float4*)(cw + (c4+2)*4);
  float4 w3 = *(const float4*)(cw + (c4+3)*4);
  float4 a = *(const float4*)(cb + c4);
#pragma unroll
  for (int k = 0; k < 4; ++k) {
    int tin = l - 3 + k;
    if (tin >= 0) {
      float4 v = *(const float4*)(zx + ((size_t)b*LH + tin)*DPROJ + DIN + c4);
      a.x += v.x * ((const float*)&w0)[k];
      a.y += v.y * ((const float*)&w1)[k];
      a.z += v.z * ((const float*)&w2)[k];
      a.w += v.w * ((const float*)&w3)[k];
    }
  }
  float4 o;
  o.x = siluf_(a.x); o.y = siluf_(a.y); o.z = siluf_(a.z); o.w = siluf_(a.w);
  *(float4*)(xbc + ((size_t)b*LH + l)*CONVD + c4) = o;
}

// ---------------------------------------------------------------- chunked SSD, phase A
// G[n][p] = sum_s (coef_s*B_s[n]) * X_s[p]  via bf16x3 MFMA. (R16-verified.)
__global__ void __launch_bounds__(256) k_chunk_state(
    const float* __restrict__ zx, const float* __restrict__ xbc,
    const float* __restrict__ A_log, float* __restrict__ G, float* __restrict__ dec) {
  int blk = blockIdx.x;
  int c = blk & (NCH-1), hd = (blk >> 5) & 3, b = blk >> 7;
  int t0 = c*QC;
  int tid = threadIdx.x;
  int wv = tid >> 6, lane = tid & 63;
  int m = lane & 15, q = lane >> 4;
  float A = -__expf(A_log[hd]);
  __shared__ __align__(16) unsigned short BcH[QC*LDS2], BcL[QC*LDS2]; // [n][s]
  __shared__ __align__(16) unsigned short XtH[QC*LDS2], XtL[QC*LDS2]; // [p][s]
  __shared__ float coef[QC];
  if (tid < 64) {
    int tg = t0 + tid;
    float dtv = (tg < LH) ? zx[((size_t)b*LH + tg)*DPROJ + 640 + hd] : 0.f;
    float s = dtv;
#pragma unroll
    for (int off = 1; off < 64; off <<= 1) {
      float u = __shfl_up(s, off);
      if (tid >= off) s += u;
    }
    float cq = __shfl(s, 63);
    coef[tid] = __expf(A*(cq - s)) * dtv;
    if (tid == 63) dec[blk] = __expf(A * s);
  }
  __syncthreads();
  for (int i = tid; i < 2048; i += 256) {
    int n = i & 63, s2 = (i >> 6)*2;
    int tg0 = t0 + s2, tg1 = t0 + s2 + 1;
    float b0 = 0.f, b1 = 0.f, x0 = 0.f, x1 = 0.f;
    if (tg0 < LH) {
      size_t row = ((size_t)b*LH + tg0)*CONVD;
      b0 = xbc[row + DIN + n] * coef[s2];
      x0 = xbc[row + hd*PDIM + n];
    }
    if (tg1 < LH) {
      size_t row = ((size_t)b*LH + tg1)*CONVD;
      b1 = xbc[row + DIN + n] * coef[s2+1];
      x1 = xbc[row + hd*PDIM + n];
    }
    int o = n*LDS2 + s2;
    *(unsigned int*)(BcH + o) = pack2(b0, b1);
    *(unsigned int*)(BcL + o) = pack2lo(b0, b1);
    *(unsigned int*)(XtH + o) = pack2(x0, x1);
    *(unsigned int*)(XtL + o) = pack2lo(x0, x1);
  }
  __syncthreads();
  bf16x8 ah[2], al[2];
#pragma unroll
  for (int kc = 0; kc < 2; ++kc) {
    int off = (wv*16 + m)*LDS2 + kc*32 + q*8;
    ah[kc] = ldfrag(BcH, off);
    al[kc] = ldfrag(BcL, off);
  }
#pragma unroll
  for (int nt = 0; nt < 4; ++nt) {
    f32x4 acc = {0.f,0.f,0.f,0.f};
#pragma unroll
    for (int kc = 0; kc < 2; ++kc) {
      int off = (nt*16 + m)*LDS2 + kc*32 + q*8;
      bf16x8 xh = ldfrag(XtH, off), xl = ldfrag(XtL, off);
      acc = __builtin_amdgcn_mfma_f32_16x16x32_bf16(al[kc], xh, acc, 0, 0, 0);
      acc = __builtin_amdgcn_mfma_f32_16x16x32_bf16(ah[kc], xl, acc, 0, 0, 0);
      acc = __builtin_amdgcn_mfma_f32_16x16x32_bf16(ah[kc], xh, acc, 0, 0, 0);
    }
    int p = nt*16 + m;
#pragma unroll
    for (int r = 0; r < 4; ++r) {
      int n = wv*16 + q*4 + r;
      G[(size_t)blk*4096 + n*64 + p] = acc[r];
    }
  }
}

// ---------------------------------------------------------------- phase B: inter-chunk
__global__ void __launch_bounds__(256) k_combine(
    const float* __restrict__ G, const float* __restrict__ dec, float* __restrict__ Hin) {
  int bh = blockIdx.x >> 2, esp = blockIdx.x & 3;
  int e = esp*1024 + threadIdx.x*4;
  size_t base0 = (size_t)bh*NCH*4096 + e;
  float4 H = make_float4(0.f,0.f,0.f,0.f);
  float4 g = *(const float4*)(G + base0);
  float d = dec[bh*NCH];
  for (int c = 0; c < NCH; ++c) {
    float4 gn = make_float4(0.f,0.f,0.f,0.f); float dn = 0.f;
    if (c + 1 < NCH) {
      gn = *(const float4*)(G + base0 + (size_t)(c+1)*4096);
      dn = dec[bh*NCH + c + 1];
    }
    *(float4*)(Hin + base0 + (size_t)c*4096) = H;   // carry-in for chunk c
    H.x = H.x*d + g.x; H.y = H.y*d + g.y; H.z = H.z*d + g.z; H.w = H.w*d + g.w;
    g = gn; d = dn;
  }
}

// ---------------------------------------------------------------- phase C: chunk output
// All three 64^3 matmuls on bf16x3 MFMA; fp32 mask/scalars. (R15-verified.)
__global__ void __launch_bounds__(256) k_chunk_out(
    const float* __restrict__ zx, const float* __restrict__ xbc,
    const float* __restrict__ A_log, const float* __restrict__ Hin,
    float* __restrict__ y) {
  int blk = blockIdx.x;
  int c = blk & (NCH-1), hd = (blk >> 5) & 3, b = blk >> 7;
  int t0 = c*QC;
  int tid = threadIdx.x;
  int wv = tid >> 6, lane = tid & 63;
  int m = lane & 15, q = lane >> 4;
  float A = -__expf(A_log[hd]);
  __shared__ __align__(16) unsigned short CH[QC*LDS2], CL[QC*LDS2]; // C [t][n]
  __shared__ __align__(16) unsigned short BH[QC*LDS2], BL[QC*LDS2]; // B [s][n] -> M [t][s]
  __shared__ __align__(16) unsigned short TH[QC*LDS2], TL[QC*LDS2]; // HT [p][n] -> Xt [p][s]
  __shared__ float cum[QC], dts[QC], pref[QC];
  if (tid < 64) {
    int tg = t0 + tid;
    float dtv = (tg < LH) ? zx[((size_t)b*LH + tg)*DPROJ + 640 + hd] : 0.f;
    float s = dtv;
#pragma unroll
    for (int off = 1; off < 64; off <<= 1) {
      float u = __shfl_up(s, off);
      if (tid >= off) s += u;
    }
    dts[tid] = dtv; cum[tid] = s; pref[tid] = __expf(A*s);
  }
  for (int i = tid; i < 2048; i += 256) {
    int s = i >> 5, j2 = (i & 31)*2;
    int tg = t0 + s;
    float b0 = 0.f, b1 = 0.f, c0_ = 0.f, c1_ = 0.f;
    if (tg < LH) {
      size_t row = ((size_t)b*LH + tg)*CONVD;
      float2 bv = *(const float2*)(xbc + row + DIN + j2);
      float2 cv = *(const float2*)(xbc + row + DIN + NSTATE + j2);
      b0 = bv.x; b1 = bv.y; c0_ = cv.x; c1_ = cv.y;
    }
    int o = s*LDS2 + j2;
    *(unsigned int*)(BH + o) = pack2(b0, b1);
    *(unsigned int*)(BL + o) = pack2lo(b0, b1);
    *(unsigned int*)(CH + o) = pack2(c0_, c1_);
    *(unsigned int*)(CL + o) = pack2lo(c0_, c1_);
  }
  size_t hbase = (size_t)blk*4096;
  for (int i = tid; i < 2048; i += 256) {
    int p = i & 63, n2 = (i >> 6)*2;
    float v0 = Hin[hbase + (size_t)n2*64 + p];
    float v1 = Hin[hbase + (size_t)(n2+1)*64 + p];
    int o = p*LDS2 + n2;
    *(unsigned int*)(TH + o) = pack2(v0, v1);
    *(unsigned int*)(TL + o) = pack2lo(v0, v1);
  }
  __syncthreads();
  bf16x8 ch[2], cl[2];
#pragma unroll
  for (int kc = 0; kc < 2; ++kc) {
    int off = (wv*16 + m)*LDS2 + kc*32 + q*8;
    ch[kc] = ldfrag(CH, off);
    cl[kc] = ldfrag(CL, off);
  }
  f32x4 sacc[4], y2a[4];
#pragma unroll
  for (int nt = 0; nt < 4; ++nt) {
    f32x4 a1 = {0.f,0.f,0.f,0.f}, a2 = {0.f,0.f,0.f,0.f};
#pragma unroll
    for (int kc = 0; kc < 2; ++kc) {
      int off = (nt*16 + m)*LDS2 + kc*32 + q*8;
      bf16x8 bh = ldfrag(BH, off), bl = ldfrag(BL, off);
      bf16x8 th = ldfrag(TH, off), tl = ldfrag(TL, off);
      a1 = __builtin_amdgcn_mfma_f32_16x16x32_bf16(cl[kc], bh, a1, 0, 0, 0);
      a1 = __builtin_amdgcn_mfma_f32_16x16x32_bf16(ch[kc], bl, a1, 0, 0, 0);
      a1 = __builtin_amdgcn_mfma_f32_16x16x32_bf16(ch[kc], bh, a1, 0, 0, 0);
      a2 = __builtin_amdgcn_mfma_f32_16x16x32_bf16(cl[kc], th, a2, 0, 0, 0);
      a2 = __builtin_amdgcn_mfma_f32_16x16x32_bf16(ch[kc], tl, a2, 0, 0, 0);
      a2 = __builtin_amdgcn_mfma_f32_16x16x32_bf16(ch[kc], th, a2, 0, 0, 0);
    }
    sacc[nt] = a1; y2a[nt] = a2;
  }
  __syncthreads();   // all waves done reading BH/TH before overwrite
#pragma unroll
  for (int nt = 0; nt < 4; ++nt) {
    int s = nt*16 + m;
#pragma unroll
    for (int r = 0; r < 4; ++r) {
      int t = wv*16 + q*4 + r;
      float mv = 0.f;
      if (s <= t) mv = sacc[nt][r] * __expf(A*(cum[t] - cum[s])) * dts[s];
      unsigned short hi = f2bf(mv);
      BH[t*LDS2 + s] = hi;
      BL[t*LDS2 + s] = f2bf(mv - bf2f(hi));
    }
  }
  for (int i = tid; i < 2048; i += 256) {
    int p = i & 63, s2 = (i >> 6)*2;
    int tg = t0 + s2;
    float v0 = (tg < LH)   ? xbc[((size_t)b*LH + tg)*CONVD + hd*PDIM + p]   : 0.f;
    float v1 = (tg+1 < LH) ? xbc[((size_t)b*LH + tg+1)*CONVD + hd*PDIM + p] : 0.f;
    int o = p*LDS2 + s2;
    *(unsigned int*)(TH + o) = pack2(v0, v1);
    *(unsigned int*)(TL + o) = pack2lo(v0, v1);
  }
  __syncthreads();
  bf16x8 mh[2], ml[2];
#pragma unroll
  for (int kc = 0; kc < 2; ++kc) {
    int off = (wv*16 + m)*LDS2 + kc*32 + q*8;
    mh[kc] = ldfrag(BH, off);
    ml[kc] = ldfrag(BL, off);
  }
#pragma unroll
  for (int nt = 0; nt < 4; ++nt) {
    f32x4 a1 = {0.f,0.f,0.f,0.f};
#pragma unroll
    for (int kc = 0; kc < 2; ++kc) {
      int off = (nt*16 + m)*LDS2 + kc*32 + q*8;
      bf16x8 th = ldfrag(TH, off), tl = ldfrag(TL, off);
      a1 = __builtin_amdgcn_mfma_f32_16x16x32_bf16(ml[kc], th, a1, 0, 0, 0);
      a1 = __builtin_amdgcn_mfma_f32_16x16x32_bf16(mh[kc], tl, a1, 0, 0, 0);
      a1 = __builtin_amdgcn_mfma_f32_16x16x32_bf16(mh[kc], th, a1, 0, 0, 0);
    }
    int p = nt*16 + m;
#pragma unroll
    for (int r = 0; r < 4; ++r) {
      int t = wv*16 + q*4 + r, tg = t0 + t;
      if (tg < LH)
        y[((size_t)b*LH + tg)*DIN + hd*PDIM + p] = a1[r] + pref[t]*y2a[nt][r];
    }
  }
}

// ---------------------------------------------------------------- gate+rmsnorm+out_proj
// FUSED with next layer's in_proj (doProj=1). 16 tokens/block; out_proj D-frags
// round-trip through LDS (8.7 KB) into the in_proj MFMA. No cross-block hazard:
// block reads z/xbc/y and writes zx only for its own 16 token-rows.
// Final layer (doProj=0): writes h fp32 directly into d_out region.
__global__ void __launch_bounds__(256) k_out_fused(
    const float* __restrict__ y, const float* __restrict__ xbc,
    float* __restrict__ zx, const float* __restrict__ Dh,
    const float* __restrict__ nw, const unsigned short* __restrict__ oH,
    const unsigned short* __restrict__ oL,
    const unsigned short* __restrict__ wH, const unsigned short* __restrict__ wL,
    const float* __restrict__ dtb, float* __restrict__ hout, int doProj) {
  int b = blockIdx.x >> 7;
  int l0 = (blockIdx.x & 127) * 16;
  int t = threadIdx.x;
  __shared__ __align__(16) unsigned short yH[16*LDSY], yL[16*LDSY];
  __shared__ __align__(16) unsigned short hsH[16*LDSH], hsL[16*LDSH];
  __shared__ float red[16][4];
  __shared__ float rs[16];
  int c = t;
  int hd = c >> 6;
  float dcoef = Dh[hd];
  float nwc = nw[c];
  float v[16];
#pragma unroll
  for (int r = 0; r < 16; ++r) {
    int l = l0 + r;
    float val = 0.f;
    if (l < LH) {
      size_t row = (size_t)b*LH + l;
      float ys = y[row*DIN + c];
      float xh = xbc[row*CONVD + c];
      float z  = zx[row*DPROJ + c];
      val = (ys + dcoef*xh) * siluf_(z);
    }
    v[r] = val;
  }
  int wave = t >> 6, lane = t & 63;
#pragma unroll
  for (int r = 0; r < 16; ++r) {
    float sq = v[r]*v[r];
    for (int off = 32; off > 0; off >>= 1) sq += __shfl_down(sq, off);
    if (lane == 0) red[r][wave] = sq;
  }
  __syncthreads();
  if (t < 16) {
    float sm = red[t][0]+red[t][1]+red[t][2]+red[t][3];
    rs[t] = rsqrtf(sm/(float)DIN + 1e-5f);
  }
  __syncthreads();
#pragma unroll
  for (int r = 0; r < 16; ++r) {
    float val = v[r] * rs[r] * nwc;
    unsigned short hi = f2bf(val);
    yH[r*LDSY + c] = hi;
    yL[r*LDSY + c] = f2bf(val - bf2f(hi));
  }
  __syncthreads();
  int m = lane & 15, q = lane >> 4;
  {
    bf16x8 ah[8], al[8];
#pragma unroll
    for (int kb = 0; kb < 8; ++kb) {
      int off = m*LDSY + kb*32 + q*8;
      ah[kb] = ldfrag(yH, off);
      al[kb] = ldfrag(yL, off);
    }
#pragma unroll
    for (int jtp = 0; jtp < 2; ++jtp) {
      int jt = wave*2 + jtp;
      f32x4 acc = {0.f,0.f,0.f,0.f};
#pragma unroll
      for (int kb = 0; kb < 8; ++kb) {
        size_t woff = (((size_t)jt*8 + kb)*64 + lane)*8;   // coalesced
        bf16x8 bh = *(const bf16x8*)(oH + woff);
        bf16x8 bl = *(const bf16x8*)(oL + woff);
        acc = __builtin_amdgcn_mfma_f32_16x16x32_bf16(al[kb], bh, acc, 0, 0, 0);
        acc = __builtin_amdgcn_mfma_f32_16x16x32_bf16(ah[kb], bl, acc, 0, 0, 0);
        acc = __builtin_amdgcn_mfma_f32_16x16x32_bf16(ah[kb], bh, acc, 0, 0, 0);
      }
      int j = jt*16 + m;                    // D col = lane&15
#pragma unroll
      for (int r = 0; r < 4; ++r) {
        int rr = q*4 + r;                   // D row = token-in-block
        float val = acc[r];                 // invalid rows produce 0 naturally
        unsigned short hi = f2bf(val);
        hsH[rr*LDSH + j] = hi;
        hsL[rr*LDSH + j] = f2bf(val - bf2f(hi));
        int l = l0 + rr;
        if (!doProj && l < LH) hout[((size_t)b*LH + l)*DIM + j] = val;
      }
    }
  }
  if (!doProj) return;
  __syncthreads();
  // ---- in_proj of next layer from the LDS h tile
  bf16x8 ah[4], al[4];
#pragma unroll
  for (int kb = 0; kb < 4; ++kb) {
    int off = m*LDSH + kb*32 + q*8;
    ah[kb] = ldfrag(hsH, off);
    al[kb] = ldfrag(hsL, off);
  }
#pragma unroll 2
  for (int jt = wave; jt < NJT; jt += 4) {
    size_t woff = (((size_t)jt*4)*64 + lane)*8;
    bf16x8 bh[4], bl[4];
#pragma unroll
    for (int kb = 0; kb < 4; ++kb) {
      bh[kb] = *(const bf16x8*)(wH + woff + (size_t)kb*64*8);  // coalesced
      bl[kb] = *(const bf16x8*)(wL + woff + (size_t)kb*64*8);
    }
    f32x4 acc = {0.f, 0.f, 0.f, 0.f};
#pragma unroll
    for (int kb = 0; kb < 4; ++kb)
      acc = __builtin_amdgcn_mfma_f32_16x16x32_bf16(al[kb], bh[kb], acc, 0, 0, 0);
#pragma unroll
    for (int kb = 0; kb < 4; ++kb)
      acc = __builtin_amdgcn_mfma_f32_16x16x32_bf16(ah[kb], bl[kb], acc, 0, 0, 0);
#pragma unroll
    for (int kb = 0; kb < 4; ++kb)
      acc = __builtin_amdgcn_mfma_f32_16x16x32_bf16(ah[kb], bh[kb], acc, 0, 0, 0);
    int jj = jt*16 + m;
    if (jj < DPROJ) {
      bool isdt = (jj >= 640);
      float bias = isdt ? dtb[jj - 640] : 0.f;
#pragma unroll
      for (int r = 0; r < 4; ++r) {
        int tok = l0 + q*4 + r;
        if (tok < LH) {
          float vv = acc[r];
          if (isdt) { vv += bias; vv = (vv > 20.f) ? vv : log1pf(__expf(vv)); }
          zx[((size_t)b*LH + tok)*DPROJ + jj] = vv;
        }
      }
    }
  }
}

// ---------------------------------------------------------------- final LN + head
__global__ void k_head(const float* __restrict__ h, const float* __restrict__ lnw,
                       const float* __restrict__ lnb, const float* __restrict__ hw,
                       const float* __restrict__ hb, float* __restrict__ out) {
  int b = blockIdx.x; int t = threadIdx.x;
  __shared__ float red[2];
  int wave = t >> 6, lane = t & 63;
  float v = h[((size_t)b*LH + LSEQ)*DIM + t];
  float s = v;
  for (int off = 32; off > 0; off >>= 1) s += __shfl_down(s, off);
  if (lane == 0) red[wave] = s;
  __syncthreads();
  float mean = (red[0]+red[1]) / (float)DIM;
  __syncthreads();
  float d = v - mean; float sq = d*d;
  for (int off = 32; off > 0; off >>= 1) sq += __shfl_down(sq, off);
  if (lane == 0) red[wave] = sq;
  __syncthreads();
  float var = (red[0]+red[1]) / (float)DIM;
  float cn = d*rsqrtf(var + 1e-5f)*lnw[t] + lnb[t];
  float dot = cn*hw[t];
  __syncthreads();
  for (int off = 32; off > 0; off >>= 1) dot += __shfl_down(dot, off);
  if (lane == 0) red[wave] = dot;
  __syncthreads();
  if (t == 0) out[b] = red[0]+red[1] + hb[0];
}

extern "C" void kernel_launch(void* const* d_in, const int* in_sizes, int n_in,
                              void* d_out, int out_size, void* d_ws, size_t ws_size,
                              hipStream_t stream) {
  const float* x     = (const float*)d_in[0];
  const float* w1    = (const float*)d_in[1];
  const float* b1    = (const float*)d_in[2];
  const float* w2    = (const float*)d_in[3];
  const float* b2    = (const float*)d_in[4];
  const float* cls   = (const float*)d_in[5];
  const float* inw   = (const float*)d_in[6];   // (4, 644, 128)
  const float* cw    = (const float*)d_in[7];   // (4, 384, 4)
  const float* cb    = (const float*)d_in[8];   // (4, 384)
  const float* dtb   = (const float*)d_in[9];   // (4, 4)
  const float* Alog  = (const float*)d_in[10];  // (4, 4)
  const float* Dh    = (const float*)d_in[11];  // (4, 4)
  const float* nw    = (const float*)d_in[12];  // (4, 256)
  const float* ow    = (const float*)d_in[13];  // (4, 128, 256)
  const float* lnw   = (const float*)d_in[14];
  const float* lnb   = (const float*)d_in[15];
  const float* hw    = (const float*)d_in[16];
  const float* hb    = (const float*)d_in[17];

  float* ws   = (float*)d_ws;
  float* zx   = ws;                                   // 10,535,840
  float* xbc  = zx + (size_t)BATCH*LH*DPROJ;          // 6,282,240
  float* ybuf = xbc + (size_t)BATCH*LH*CONVD;         // 4,194,304 (G aliases ybuf)
  float* G    = ybuf;
  float* Hin  = ybuf + 4194304;                       // 4,194,304
  float* dec  = Hin  + 4194304;                       // 1,024
  unsigned short* hH = (unsigned short*)(dec + 1024);      // 8*2048*128 u16
  unsigned short* hL = hH + (size_t)BATCH*LHP*DIM;         // 8*2048*128 u16
  unsigned short* wH = hL + (size_t)BATCH*LHP*DIM;         // 4*41*4*64*8 u16
  unsigned short* wL = wH + (size_t)DEPTH*NJT*4*64*8;      // same
  unsigned short* oH = wL + (size_t)DEPTH*NJT*4*64*8;      // 4*8*8*64*8 u16
  unsigned short* oL = oH + (size_t)DEPTH*8*8*64*8;        // same
  // total ~27.8M floats-equivalent = ~111 MiB

  float* hout = (float*)d_out + 8;   // final h written directly into output

  k_cast_w<<<(DEPTH*NJT*4*64 + 255)/256, 256, 0, stream>>>(inw, wH, wL);
  k_cast_ow<<<(DEPTH*8*8*64 + 255)/256, 256, 0, stream>>>(ow, oH, oL);

  k_front<<<BATCH*64 + 1, 256, 0, stream>>>(x, w1, b1, w2, b2, cls, hH, hL);
  k_inproj_mfma<<<BATCH*64, 256, 0, stream>>>(hH, hL, wH, wL, dtb, zx);

  for (int i = 0; i < DEPTH; ++i) {
    int doProj = (i < DEPTH-1) ? 1 : 0;
    int nxt = doProj ? (i+1) : 0;
    k_conv<<<(int)(((long)BATCH*LH*(CONVD/4) + 255)/256), 256, 0, stream>>>(
        zx, cw + (size_t)i*CONVD*4, cb + (size_t)i*CONVD, xbc);
    k_chunk_state<<<BATCH*NH*NCH, 256, 0, stream>>>(zx, xbc, Alog + i*NH, G, dec);
    k_combine<<<BATCH*NH*4, 256, 0, stream>>>(G, dec, Hin);
    k_chunk_out<<<BATCH*NH*NCH, 256, 0, stream>>>(zx, xbc, Alog + i*NH, Hin, ybuf);
    k_out_fused<<<BATCH*128, 256, 0, stream>>>(
        ybuf, xbc, zx, Dh + i*NH, nw + (size_t)i*DIN,
        oH + (size_t)i*8*8*64*8, oL + (size_t)i*8*8*64*8,
        wH + (size_t)nxt*NJT*4*64*8, wL + (size_t)nxt*NJT*4*64*8,
        dtb + nxt*NH, hout, doProj);
  }

  k_head<<<BATCH, 128, 0, stream>>>(hout, lnw, lnb, hw, hb, (float*)d_out);
}